// Round 2
// baseline (215.700 us; speedup 1.0000x reference)
//
#include <hip/hip_runtime.h>
#include <stdint.h>

#define LOG2E 1.4426950408889634f
#define QSCALE 0.18033688011112042f  // 0.125 * log2(e), folded into Q at GEMM1

typedef __attribute__((ext_vector_type(8))) short bf16x8;
typedef __attribute__((ext_vector_type(4))) float f32x4;
typedef __attribute__((ext_vector_type(8))) unsigned short u16x8;

#define B_ 2
#define T_ 2048
#define C_ 1024
#define H_ 16
#define D_ 64
#define BT_ 4096
#define N3_ 3072

#if __has_builtin(__builtin_amdgcn_exp2f)
#define EXP2(x) __builtin_amdgcn_exp2f(x)   // raw v_exp_f32 (inputs bounded, no denorm path)
#else
#define EXP2(x) exp2f(x)
#endif

__device__ __forceinline__ unsigned short f2bf(float f) {
  union { float f; unsigned u; } x; x.f = f;
  return (unsigned short)((x.u + 0x7fffu + ((x.u >> 16) & 1u)) >> 16);
}
__device__ __forceinline__ float bf2f(unsigned short u) {
  union { unsigned u; float f; } x; x.u = ((unsigned)u) << 16;
  return x.f;
}
__device__ __forceinline__ unsigned f2u(float f) {
  union { float f; unsigned u; } x; x.f = f; return x.u;
}
// pack two f32 -> dword of 2 bf16 (low short = a, high = b), round-nearest-away
__device__ __forceinline__ unsigned pack_bf2(float a, float b) {
  return __builtin_amdgcn_perm(f2u(b) + 0x8000u, f2u(a) + 0x8000u, 0x07060302u);
}

// async global->LDS 16B (m97 pattern). LDS dest must be wave-uniform base +
// lane*16 — all call sites below keep lds addr == linear(slot)*16B.
__device__ __forceinline__ void gld16(const unsigned short* g, unsigned short* l) {
  __builtin_amdgcn_global_load_lds(
      (const __attribute__((address_space(1))) unsigned int*)g,
      (__attribute__((address_space(3))) unsigned int*)l, 16, 0, 0);
}

// ---------------- prep (r11-proven): cvt + 2 transposes in one launch ---------
__device__ __forceinline__ void tr32(const float* __restrict__ in,
                                     unsigned short* __restrict__ out,
                                     int K, int N, int b, int nbx, int tid) {
  __shared__ unsigned short tile[32][33];
  const int bx = b % nbx, by = b / nbx;
  const int n0 = bx * 32, k0 = by * 32;
  const int tx = tid & 31, ty = (tid >> 5) * 4;
#pragma unroll
  for (int r = 0; r < 4; r++)
    tile[ty + r][tx] = f2bf(in[(size_t)(k0 + ty + r) * N + n0 + tx]);
  __syncthreads();
#pragma unroll
  for (int r = 0; r < 4; r++)
    out[(size_t)(n0 + ty + r) * K + k0 + tx] = tile[tx][ty + r];
}

__global__ __launch_bounds__(256) void prep_kernel(
    const float* __restrict__ x, unsigned short* __restrict__ xb,
    const float* __restrict__ wq, unsigned short* __restrict__ wqT,
    const float* __restrict__ wp, unsigned short* __restrict__ wpT) {
  const int bid = blockIdx.x, tid = threadIdx.x;
  if (bid < 4096) {
    int i = (bid * 256 + tid) * 4;
    float4 v = *(const float4*)(x + i);
    ushort4 o;
    o.x = f2bf(v.x); o.y = f2bf(v.y); o.z = f2bf(v.z); o.w = f2bf(v.w);
    *(ushort4*)(xb + i) = o;
  } else if (bid < 4096 + 3072) {
    tr32(wq, wqT, 1024, 3072, bid - 4096, 96, tid);
  } else {
    tr32(wp, wpT, 1024, 1024, bid - 7168, 32, tid);
  }
}

// stage one 128x64 half-tile: local rows 0..127 of matrix G (ld=1024, bf16)
// into LDS at L (linear 16B slots, chunk-swizzled), 2 gld16/thread (512 thr).
__device__ __forceinline__ void stage128(const unsigned short* __restrict__ G,
                                         unsigned short* L, int k, int tid) {
#pragma unroll
  for (int j = 0; j < 2; j++) {
    const int s = tid + 512 * j;          // 0..1023
    const int row = s >> 3, ch = s & 7;   // row 0..127, chunk 0..7
    gld16(G + (size_t)row * 1024 + k + ((ch ^ (row & 7)) * 8), L + s * 8);
  }
}

// ---------------- GEMM1: 256x256 8-phase counted-vmcnt schedule (m201 port) --
// M=4096 N=3072 K=1024. Grid 192 blocks (XCD-swizzled), 512 thr (8 waves 2Mx4N),
// per-wave 128x64 output acc[8][4], LDS 128KB = 2 dbuf x (A 256x64 + B 256x64).
// Per K-tile: 4 phases, each = {stage 1 half of next K-tile into idle buffer;
// [p0: s_waitcnt vmcnt(2)]; s_barrier; 12 ds_read_b128 (one acc quadrant);
// setprio(1); 16 MFMA; setprio(0); s_barrier}. vmcnt never drains to 0 in the
// main loop (except final tile). Overwrite safety: all ds_reads of a buffer are
// consumed (compiler lgkmcnt) before the phase-end barrier; stores into that
// buffer issue only after the next phase begins.
// Epilogue: scatter q*QSCALE [B,H,T,D], k [B,H,T,D], v [B,H,D,T] bf16.
__global__ __launch_bounds__(512, 2) void gemm1_kernel(
    const unsigned short* __restrict__ A, const unsigned short* __restrict__ Bt,
    unsigned short* __restrict__ qo, unsigned short* __restrict__ ko,
    unsigned short* __restrict__ vo) {
  __shared__ unsigned short As[2][256 * 64];  // 32KB per buffer
  __shared__ unsigned short Bs[2][256 * 64];  // 32KB per buffer
  const int tid = threadIdx.x;
  const int wid = tid >> 6, lane = tid & 63;
  const int quad = lane >> 4, l16 = lane & 15;
  const int wm = (wid >> 2) * 128, wn = (wid & 3) * 64;

  // XCD-aware bijective swizzle over 192 blocks (192 % 8 == 0)
  const int id = blockIdx.x;
  const int swz = (id & 7) * 24 + (id >> 3);
  const int mb = swz / 12, nb = swz % 12;
  const int m0 = mb * 256, n0 = nb * 256;

  f32x4 acc[8][4] = {};  // 128 VGPR accumulator

  // prologue: stage K-tile 0 into buffer 0 (8 loads/thread, left in flight)
  stage128(A + (size_t)m0 * 1024,         &As[0][0],    0, tid);
  stage128(A + (size_t)(m0 + 128) * 1024, &As[0][8192], 0, tid);
  stage128(Bt + (size_t)n0 * 1024,        &Bs[0][0],    0, tid);
  stage128(Bt + (size_t)(n0 + 128) * 1024,&Bs[0][8192], 0, tid);

  for (int kt = 0; kt < 16; kt++) {
    const int cur = kt & 1;
    const int knext = (kt + 1) * 64;
#pragma unroll
    for (int p = 0; p < 4; p++) {
      // stage half p of next K-tile into the idle buffer
      if (kt < 15) {
        if (p == 0)
          stage128(A + (size_t)m0 * 1024, &As[cur ^ 1][0], knext, tid);
        else if (p == 1)
          stage128(A + (size_t)(m0 + 128) * 1024, &As[cur ^ 1][8192], knext, tid);
        else if (p == 2)
          stage128(Bt + (size_t)n0 * 1024, &Bs[cur ^ 1][0], knext, tid);
        else
          stage128(Bt + (size_t)(n0 + 128) * 1024, &Bs[cur ^ 1][8192], knext, tid);
      }
      if (p == 0) {
        // previous K-tile's 8 loads must land; the 2 just issued stay in flight
        if (kt < 15) asm volatile("s_waitcnt vmcnt(2)" ::: "memory");
        else         asm volatile("s_waitcnt vmcnt(0)" ::: "memory");
      }
      __builtin_amdgcn_s_barrier();
      __builtin_amdgcn_sched_barrier(0);

      // ds_read one acc quadrant: mh = p>>1 (m-frags), nh = p&1 (n-frags)
      const int mh = p >> 1, nh = p & 1;
      bf16x8 af[4][2], bfr[2][2];
#pragma unroll
      for (int mi = 0; mi < 4; mi++) {
        const int row = wm + (mh * 4 + mi) * 16 + l16;
        const int sw = row & 7;
#pragma unroll
        for (int ks = 0; ks < 2; ks++)
          af[mi][ks] = *(const bf16x8*)(&As[cur][0] + row * 64 + (((ks * 4 + quad) ^ sw) * 8));
      }
#pragma unroll
      for (int ni = 0; ni < 2; ni++) {
        const int row = wn + (nh * 2 + ni) * 16 + l16;
        const int sw = row & 7;
#pragma unroll
        for (int ks = 0; ks < 2; ks++)
          bfr[ni][ks] = *(const bf16x8*)(&Bs[cur][0] + row * 64 + (((ks * 4 + quad) ^ sw) * 8));
      }

      __builtin_amdgcn_s_setprio(1);
#pragma unroll
      for (int ks = 0; ks < 2; ks++)
#pragma unroll
        for (int mi = 0; mi < 4; mi++)
#pragma unroll
          for (int ni = 0; ni < 2; ni++)
            acc[mh * 4 + mi][nh * 2 + ni] = __builtin_amdgcn_mfma_f32_16x16x32_bf16(
                af[mi][ks], bfr[ni][ks], acc[mh * 4 + mi][nh * 2 + ni], 0, 0, 0);
      __builtin_amdgcn_s_setprio(0);
      __builtin_amdgcn_s_barrier();
    }
  }

  // epilogue: C/D layout col=l16, row=quad*4+r (m89/m91-verified).
  // n0 is a multiple of 256 -> tile entirely within one of q/k/v (1024 each);
  // per-wave 64 cols = exactly one head.
  const int part = n0 >> 10;
  const int hh = ((n0 + wn) >> 6) & 15;
#pragma unroll
  for (int mi8 = 0; mi8 < 8; mi8++) {
#pragma unroll
    for (int r = 0; r < 4; r++) {
      const int m = m0 + wm + mi8 * 16 + quad * 4 + r;
      const int b = m >> 11, t = m & 2047;
#pragma unroll
      for (int ni = 0; ni < 4; ni++) {
        const int d = ni * 16 + l16;
        float val = acc[mi8][ni][r];
        if (part == 0) val *= QSCALE;   // fold softmax scale into Q (fp32, free)
        const unsigned short bv = f2bf(val);
        if (part == 0)
          qo[((size_t)(b * H_ + hh) * T_ + t) * D_ + d] = bv;
        else if (part == 1)
          ko[((size_t)(b * H_ + hh) * T_ + t) * D_ + d] = bv;
        else
          vo[((size_t)(b * H_ + hh) * D_ + d) * T_ + t] = bv;  // V pre-transposed [B,H,D,T]
      }
    }
  }
}

// ---------------- GEMM2: 512-thr split-K-in-block (r12) ----------------------
// r10/r11 data: per-block latency ~48us regardless of 2 or 6 blocks/CU ->
// blocks overlap freely; gemm2 (512 blocks = 2/CU) wastes the machine.
// Split K inside the block: wave-group g in {0,1} computes K in [g*512,g*512+512)
// into its own LDS tiles (8 drain-rounds instead of 16 -> ~half block latency),
// fp32 combine through LDS at the end. Tile 128x64, grid (16,32) unchanged.
__global__ __launch_bounds__(512) void gemm2_kernel(
    const unsigned short* __restrict__ A, const unsigned short* __restrict__ Bt,
    float* __restrict__ fo) {
  __shared__ unsigned short As[2][128 * 64];  // 2 x 16KB, chunk-swizzled
  __shared__ unsigned short Bs[2][64 * 64];   // 2 x 8KB, chunk-swizzled
  const int tid = threadIdx.x;
  const int wave = tid >> 6, lane = tid & 63;
  const int quad = lane >> 4, l16 = lane & 15;
  const int grp = wave >> 2, w4 = wave & 3;
  const int wm = (w4 >> 1) * 64, wn = (w4 & 1) * 32;
  const int m0 = blockIdx.y * 128, n0 = blockIdx.x * 64;
  const int gtid = tid & 255;   // group-local thread id

  f32x4 acc[4][2] = {};
  const int kbase = grp * 512;
  unsigned short* Asg = &As[grp][0];
  unsigned short* Bsg = &Bs[grp][0];

  for (int kk = 0; kk < 512; kk += 64) {
    const int k = kbase + kk;
    __syncthreads();
#pragma unroll
    for (int i = 0; i < 4; i++) {
      const int s = gtid + 256 * i;
      const int row = s >> 3, ch = s & 7;
      gld16(A + (size_t)(m0 + row) * 1024 + k + ((ch ^ (row & 7)) * 8), Asg + s * 8);
    }
#pragma unroll
    for (int i = 0; i < 2; i++) {
      const int s = gtid + 256 * i;
      const int row = s >> 3, ch = s & 7;
      gld16(Bt + (size_t)(n0 + row) * 1024 + k + ((ch ^ (row & 7)) * 8), Bsg + s * 8);
    }
    __syncthreads();
#pragma unroll
    for (int sub = 0; sub < 2; sub++) {
      bf16x8 af[4], bfr[2];
#pragma unroll
      for (int mi = 0; mi < 4; mi++) {
        const int row = wm + mi * 16 + l16;
        af[mi] = *(const bf16x8*)(Asg + row * 64 + (((sub * 4 + quad) ^ (row & 7)) * 8));
      }
#pragma unroll
      for (int ni = 0; ni < 2; ni++) {
        const int row = wn + ni * 16 + l16;
        bfr[ni] = *(const bf16x8*)(Bsg + row * 64 + (((sub * 4 + quad) ^ (row & 7)) * 8));
      }
#pragma unroll
      for (int mi = 0; mi < 4; mi++)
#pragma unroll
        for (int ni = 0; ni < 2; ni++)
          acc[mi][ni] = __builtin_amdgcn_mfma_f32_16x16x32_bf16(af[mi], bfr[ni], acc[mi][ni], 0, 0, 0);
    }
  }

  // combine: group 1 -> LDS (reuse As, 32KB), group 0 adds + stores
  __syncthreads();
  float* comb = (float*)&As[0][0];
  if (grp == 1) {
#pragma unroll
    for (int mi = 0; mi < 4; mi++)
#pragma unroll
      for (int ni = 0; ni < 2; ni++)
        *(f32x4*)(comb + ((w4 * 8 + mi * 2 + ni) * 256 + lane * 4)) = acc[mi][ni];
  }
  __syncthreads();
  if (grp == 0) {
#pragma unroll
    for (int mi = 0; mi < 4; mi++) {
#pragma unroll
      for (int ni = 0; ni < 2; ni++) {
        f32x4 oth = *(const f32x4*)(comb + ((w4 * 8 + mi * 2 + ni) * 256 + lane * 4));
        f32x4 v = acc[mi][ni] + oth;
#pragma unroll
        for (int r = 0; r < 4; r++) {
          const int m = m0 + wm + mi * 16 + quad * 4 + r;
          fo[(size_t)m * 1024 + n0 + wn + ni * 16 + l16] = v[r];
        }
      }
    }
  }
}

// ---------------- flash attention: block staging + split-K + S^T softmax ------
// (r10 config: XCD-local bh = bid&31, longest chunks first — unchanged)
__global__ __launch_bounds__(256) void attn_kernel(
    const unsigned short* __restrict__ qb, const unsigned short* __restrict__ kb,
    const unsigned short* __restrict__ vb, unsigned short* __restrict__ yb,
    unsigned short* __restrict__ po, float* __restrict__ pl) {
  const int tid = threadIdx.x;
  const int wave = tid >> 6, lane = tid & 63;
  const int quad = lane >> 4, l16 = lane & 15;

  const int bid = blockIdx.x;
  const int bh = bid & 31;          // XCD-local: all 63 blocks of bh on one XCD
  const int u = 62 - (bid >> 5);    // longest chunks first
  int qs, c, nch;
  if (u < 11) { qs = u; c = 0; nch = 1; }
  else if (u < 33) { int v = u - 11; qs = 11 + (v >> 1); c = v & 1; nch = 2; }
  else { int v = u - 33; qs = 22 + v / 3; c = v % 3; nch = 3; }
  const int nt = qs + 1;
  const int j0 = c * nt / nch, j1 = (c + 1) * nt / nch;
  const int b = bh >> 4, h = bh & 15;

  __shared__ unsigned short Ks[64 * 64];     // [s][d], chunk-swizzled
  __shared__ unsigned short Vt[64 * 64];     // [d][s], chunk-swizzled
  __shared__ unsigned short Ps[4 * 16 * 68]; // per-wave P [q][s], stride 68
  unsigned short* Pw = Ps + wave * 16 * 68;

  const unsigned short* Qg = qb + (size_t)bh * T_ * D_;
  const unsigned short* Kg = kb + (size_t)bh * T_ * D_;
  const unsigned short* Vg = vb + (size_t)bh * D_ * T_;

  // Q fragment (B-operand: n=q=l16, k=d=quad*8+j)
  const unsigned short* qp = Qg + (size_t)(qs * 64 + wave * 16 + l16) * D_ + quad * 8;
  bf16x8 qf0 = *(const bf16x8*)qp, qf1 = *(const bf16x8*)(qp + 32);

  f32x4 o[4] = {};
  float lacc = 0.f;
  const int qglob = qs * 64 + wave * 16 + l16;   // this lane's q (S^T: col=l16)
  const int sloc_base = quad * 4;                // s-local row base (S^T: row=quad*4+r)

  const int trow = tid >> 3, tch = tid & 7;

  for (int jt = j0; jt < j1; jt++) {
    const int s0 = jt * 64;
    __syncthreads();
    {
      const int r0 = trow, r1 = trow + 32;
      gld16(Kg + (size_t)(s0 + r0) * D_ + ((tch ^ (r0 & 7)) * 8), Ks + r0 * 64 + tch * 8);
      gld16(Kg + (size_t)(s0 + r1) * D_ + ((tch ^ (r1 & 7)) * 8), Ks + r1 * 64 + tch * 8);
      gld16(Vg + (size_t)r0 * T_ + s0 + ((tch ^ (r0 & 7)) * 8), Vt + r0 * 64 + tch * 8);
      gld16(Vg + (size_t)r1 * T_ + s0 + ((tch ^ (r1 & 7)) * 8), Vt + r1 * 64 + tch * 8);
    }
    __syncthreads();

    // S^T = K Q^T : K as A-operand, Q as B-operand.
    // C-layout of s[mi]: row = s-local = mi*16+quad*4+r, col = q = l16.
    f32x4 s[4];
#pragma unroll
    for (int mi = 0; mi < 4; mi++) {
      const int row = mi * 16 + l16, sw = row & 7;
      bf16x8 kf0 = *(const bf16x8*)(Ks + row * 64 + ((quad ^ sw) * 8));
      bf16x8 kf1 = *(const bf16x8*)(Ks + row * 64 + (((quad + 4) ^ sw) * 8));
      f32x4 z = {0.f, 0.f, 0.f, 0.f};
      z = __builtin_amdgcn_mfma_f32_16x16x32_bf16(kf0, qf0, z, 0, 0, 0);
      s[mi] = __builtin_amdgcn_mfma_f32_16x16x32_bf16(kf1, qf1, z, 0, 0, 0);
    }

    if (jt == qs) {  // uniform diag branch: mask s > q
#pragma unroll
      for (int mi = 0; mi < 4; mi++)
#pragma unroll
        for (int r = 0; r < 4; r++) {
          float p = EXP2(s[mi][r]);
          p = (s0 + mi * 16 + sloc_base + r > qglob) ? 0.f : p;
          s[mi][r] = p;
          lacc += p;
        }
    } else {
#pragma unroll
      for (int mi = 0; mi < 4; mi++)
#pragma unroll
        for (int r = 0; r < 4; r++) {
          float p = EXP2(s[mi][r]);
          s[mi][r] = p;
          lacc += p;
        }
    }

    // P -> LDS [q=l16][s], packed dwords
#pragma unroll
    for (int mi = 0; mi < 4; mi++) {
      unsigned d0 = pack_bf2(s[mi][0], s[mi][1]);
      unsigned d1 = pack_bf2(s[mi][2], s[mi][3]);
      *(uint2*)(Pw + l16 * 68 + mi * 16 + quad * 4) = make_uint2(d0, d1);
    }

    // O += P V : P as A-operand (m=q=l16, k=s), V^T as B-operand
#pragma unroll
    for (int kk = 0; kk < 2; kk++) {
      bf16x8 pf = *(const bf16x8*)(Pw + l16 * 68 + kk * 32 + quad * 8);
#pragma unroll
      for (int ni = 0; ni < 4; ni++) {
        const int row = ni * 16 + l16, sw = row & 7;
        bf16x8 vf = *(const bf16x8*)(Vt + row * 64 + (((kk * 4 + quad) ^ sw) * 8));
        o[ni] = __builtin_amdgcn_mfma_f32_16x16x32_bf16(pf, vf, o[ni], 0, 0, 0);
      }
    }
  }

  // l: sum across the 4 lanes sharing l16 (quads), then fetch per-row values
  lacc += __shfl_xor(lacc, 16, 64);
  lacc += __shfl_xor(lacc, 32, 64);
  float lr[4];
#pragma unroll
  for (int r = 0; r < 4; r++) lr[r] = __shfl(lacc, quad * 4 + r, 16);  // l for q-row quad*4+r

  if (nch == 1) {
#pragma unroll
    for (int r = 0; r < 4; r++) {
      float inv = 1.0f / lr[r];
      int tq = qs * 64 + wave * 16 + quad * 4 + r;
#pragma unroll
      for (int ni = 0; ni < 4; ni++)
        yb[((size_t)(b * T_ + tq)) * 1024 + h * 64 + ni * 16 + l16] = f2bf(o[ni][r] * inv);
    }
  } else {
    const int slot = 52 * bh + ((qs <= 21) ? ((qs - 11) * 2 + c) : (22 + (qs - 22) * 3 + c));
    unsigned short* pob = po + (size_t)slot * 4096;
#pragma unroll
    for (int r = 0; r < 4; r++) {
      const int row64 = wave * 16 + quad * 4 + r;
#pragma unroll
      for (int ni = 0; ni < 4; ni++)
        pob[row64 * 64 + ni * 16 + l16] = f2bf(o[ni][r]);
      if (l16 == 0) pl[slot * 64 + row64] = lr[r];
    }
  }
}

// ---------------- split-K reduce: rows of strips qs>=11 ----------------
__global__ __launch_bounds__(256) void reduce_kernel(
    const unsigned short* __restrict__ po, const float* __restrict__ pl,
    unsigned short* __restrict__ yb) {
  int idx = blockIdx.x * 256 + threadIdx.x;
  int bh = idx / 21504;          // 1344 rows * 16 colgroups
  int rem = idx - bh * 21504;
  int rr = rem >> 4, cg = rem & 15;
  int qs = 11 + (rr >> 6), row64 = rr & 63;
  int base, nch;
  if (qs <= 21) { base = (qs - 11) * 2; nch = 2; }
  else { base = 22 + (qs - 22) * 3; nch = 3; }
  int b = bh >> 4, h = bh & 15;
  float a0 = 0.f, a1 = 0.f, a2 = 0.f, a3 = 0.f, l = 0.f;
  for (int cc = 0; cc < nch; cc++) {
    int slot = 52 * bh + base + cc;
    const unsigned short* p = po + (size_t)slot * 4096 + row64 * 64 + cg * 4;
    ushort4 uv = *(const ushort4*)p;
    a0 += bf2f(uv.x); a1 += bf2f(uv.y); a2 += bf2f(uv.z); a3 += bf2f(uv.w);
    l += pl[slot * 64 + row64];
  }
  float inv = 1.0f / l;
  int tq = qs * 64 + row64;
  ushort4 w;
  w.x = f2bf(a0 * inv); w.y = f2bf(a1 * inv); w.z = f2bf(a2 * inv); w.w = f2bf(a3 * inv);
  *(ushort4*)(yb + ((size_t)(b * T_ + tq)) * 1024 + h * 64 + cg * 4) = w;
}

// ---------------- launch ----------------
extern "C" void kernel_launch(void* const* d_in, const int* in_sizes, int n_in,
                              void* d_out, int out_size, void* d_ws, size_t ws_size,
                              hipStream_t stream) {
  const float* x = (const float*)d_in[0];       // [B,T,C]
  const float* w_qkv = (const float*)d_in[1];   // [C,3C]
  const float* w_proj = (const float*)d_in[2];  // [C,C]
  float* out = (float*)d_out;                   // [B,T,C] fp32

  // ws layout (shorts). po aliases wqkvT (dead after GEMM1). ~49.7 MB total.
  unsigned short* xb = (unsigned short*)d_ws;                 // 4.19M
  unsigned short* wprojT = xb + (size_t)BT_ * C_;             // 1.05M
  unsigned short* qb = wprojT + (size_t)C_ * C_;              // 4.19M
  unsigned short* kb = qb + (size_t)B_ * H_ * T_ * D_;        // 4.19M
  unsigned short* vb = kb + (size_t)B_ * H_ * T_ * D_;        // 4.19M
  unsigned short* wqkvT = vb + (size_t)B_ * H_ * T_ * D_;     // 3.15M
  unsigned short* po = wqkvT;                                 // 1664 slots * 4096 = 6.82M
  float* pl = (float*)(po + (size_t)1664 * 4096);             // 106K fp32
  unsigned short* yb = xb;  // reuse (x dead after GEMM1)

  prep_kernel<<<dim3(8192), 256, 0, stream>>>(x, xb, w_qkv, wqkvT, w_proj, wprojT);

  gemm1_kernel<<<dim3(192), 512, 0, stream>>>(xb, wqkvT, qb, kb, vb);
  attn_kernel<<<dim3(32 * 63), 256, 0, stream>>>(qb, kb, vb, yb, po, pl);
  reduce_kernel<<<dim3(2688), 256, 0, stream>>>(po, pl, yb);
  gemm2_kernel<<<dim3(C_ / 64, BT_ / 128), 512, 0, stream>>>(yb, wprojT, out);
}

// Round 3
// 205.934 us; speedup vs baseline: 1.0474x; 1.0474x over previous
//
#include <hip/hip_runtime.h>
#include <stdint.h>

#define LOG2E 1.4426950408889634f
#define QSCALE 0.18033688011112042f  // 0.125 * log2(e), folded into Q at GEMM1

typedef __attribute__((ext_vector_type(8))) short bf16x8;
typedef __attribute__((ext_vector_type(4))) float f32x4;
typedef __attribute__((ext_vector_type(8))) unsigned short u16x8;

#define B_ 2
#define T_ 2048
#define C_ 1024
#define H_ 16
#define D_ 64
#define BT_ 4096
#define N3_ 3072

#if __has_builtin(__builtin_amdgcn_exp2f)
#define EXP2(x) __builtin_amdgcn_exp2f(x)   // raw v_exp_f32 (inputs bounded, no denorm path)
#else
#define EXP2(x) exp2f(x)
#endif

__device__ __forceinline__ unsigned short f2bf(float f) {
  union { float f; unsigned u; } x; x.f = f;
  return (unsigned short)((x.u + 0x7fffu + ((x.u >> 16) & 1u)) >> 16);
}
__device__ __forceinline__ float bf2f(unsigned short u) {
  union { unsigned u; float f; } x; x.u = ((unsigned)u) << 16;
  return x.f;
}
__device__ __forceinline__ unsigned f2u(float f) {
  union { float f; unsigned u; } x; x.f = f; return x.u;
}
// pack two f32 -> dword of 2 bf16 (low short = a, high = b), round-nearest-away
__device__ __forceinline__ unsigned pack_bf2(float a, float b) {
  return __builtin_amdgcn_perm(f2u(b) + 0x8000u, f2u(a) + 0x8000u, 0x07060302u);
}

// async global->LDS 16B (m97 pattern). LDS dest must be wave-uniform base +
// lane*16 — all call sites below keep lds addr == linear(slot)*16B.
__device__ __forceinline__ void gld16(const unsigned short* g, unsigned short* l) {
  __builtin_amdgcn_global_load_lds(
      (const __attribute__((address_space(1))) unsigned int*)g,
      (__attribute__((address_space(3))) unsigned int*)l, 16, 0, 0);
}

// ---------------- prep (r11-proven): cvt + 2 transposes in one launch ---------
__device__ __forceinline__ void tr32(const float* __restrict__ in,
                                     unsigned short* __restrict__ out,
                                     int K, int N, int b, int nbx, int tid) {
  __shared__ unsigned short tile[32][33];
  const int bx = b % nbx, by = b / nbx;
  const int n0 = bx * 32, k0 = by * 32;
  const int tx = tid & 31, ty = (tid >> 5) * 4;
#pragma unroll
  for (int r = 0; r < 4; r++)
    tile[ty + r][tx] = f2bf(in[(size_t)(k0 + ty + r) * N + n0 + tx]);
  __syncthreads();
#pragma unroll
  for (int r = 0; r < 4; r++)
    out[(size_t)(n0 + ty + r) * K + k0 + tx] = tile[tx][ty + r];
}

__global__ __launch_bounds__(256) void prep_kernel(
    const float* __restrict__ x, unsigned short* __restrict__ xb,
    const float* __restrict__ wq, unsigned short* __restrict__ wqT,
    const float* __restrict__ wp, unsigned short* __restrict__ wpT) {
  const int bid = blockIdx.x, tid = threadIdx.x;
  if (bid < 4096) {
    int i = (bid * 256 + tid) * 4;
    float4 v = *(const float4*)(x + i);
    ushort4 o;
    o.x = f2bf(v.x); o.y = f2bf(v.y); o.z = f2bf(v.z); o.w = f2bf(v.w);
    *(ushort4*)(xb + i) = o;
  } else if (bid < 4096 + 3072) {
    tr32(wq, wqT, 1024, 3072, bid - 4096, 96, tid);
  } else {
    tr32(wp, wpT, 1024, 1024, bid - 7168, 32, tid);
  }
}

// stage one 128x64 half-tile: local rows 0..127 of matrix G (ld=1024, bf16)
// into LDS at L (linear 16B slots, chunk-swizzled), 2 gld16/thread (512 thr).
__device__ __forceinline__ void stage128(const unsigned short* __restrict__ G,
                                         unsigned short* L, int k, int tid) {
#pragma unroll
  for (int j = 0; j < 2; j++) {
    const int s = tid + 512 * j;          // 0..1023
    const int row = s >> 3, ch = s & 7;   // row 0..127, chunk 0..7
    gld16(G + (size_t)row * 1024 + k + ((ch ^ (row & 7)) * 8), L + s * 8);
  }
}

// stage a full 256x64 A-tile + 256x64 B-tile (8 gld16/thread)
__device__ __forceinline__ void stage_tile(const unsigned short* __restrict__ A,
                                           const unsigned short* __restrict__ Bt,
                                           int m0, int n0, int k,
                                           unsigned short* as, unsigned short* bs, int tid) {
  stage128(A + (size_t)m0 * 1024,          as,        k, tid);
  stage128(A + (size_t)(m0 + 128) * 1024,  as + 8192, k, tid);
  stage128(Bt + (size_t)n0 * 1024,         bs,        k, tid);
  stage128(Bt + (size_t)(n0 + 128) * 1024, bs + 8192, k, tid);
}

// fragment loads (chunk-swizzled LDS, conflict-free: bank = 4*(chunk^row&7))
template <int H>
__device__ __forceinline__ void load_a4(bf16x8 f[4][2], const unsigned short* base,
                                        int w0, int l16, int quad) {
#pragma unroll
  for (int i = 0; i < 4; i++) {
    const int row = w0 + (H * 4 + i) * 16 + l16;
    const int sw = row & 7;
#pragma unroll
    for (int ks = 0; ks < 2; ks++)
      f[i][ks] = *(const bf16x8*)(base + row * 64 + (((ks * 4 + quad) ^ sw) * 8));
  }
}
template <int H>
__device__ __forceinline__ void load_b2(bf16x8 f[2][2], const unsigned short* base,
                                        int w0, int l16, int quad) {
#pragma unroll
  for (int i = 0; i < 2; i++) {
    const int row = w0 + (H * 2 + i) * 16 + l16;
    const int sw = row & 7;
#pragma unroll
    for (int ks = 0; ks < 2; ks++)
      f[i][ks] = *(const bf16x8*)(base + row * 64 + (((ks * 4 + quad) ^ sw) * 8));
  }
}
// one C-quadrant: 16 MFMA, acc indices fully static (MH/NH template)
template <int MH, int NH>
__device__ __forceinline__ void mfma_quad(f32x4 acc[8][4], bf16x8 af[4][2], bf16x8 bfr[2][2]) {
  __builtin_amdgcn_s_setprio(1);
#pragma unroll
  for (int ks = 0; ks < 2; ks++)
#pragma unroll
    for (int mi = 0; mi < 4; mi++)
#pragma unroll
      for (int ni = 0; ni < 2; ni++)
        acc[MH * 4 + mi][NH * 2 + ni] = __builtin_amdgcn_mfma_f32_16x16x32_bf16(
            af[mi][ks], bfr[ni][ks], acc[MH * 4 + mi][NH * 2 + ni], 0, 0, 0);
  __builtin_amdgcn_s_setprio(0);
}

// ---------------- GEMM1: 256x256, deep-prefetch counted-vmcnt (r3) -----------
// M=4096 N=3072 K=1024, grid 192 (XCD-swizzled), 512 thr (8 waves 2Mx4N),
// per-wave 128x64 output acc[8][4], LDS 128KB = 2 dbuf x (A 256x64 + B 256x64).
// Round-2 postmortem: per-phase staging gave the last half-tile ~1 phase of
// latency cover at 1 block/CU -> every tile stalled (MfmaUtil 12%). Fix:
//   - stage the ENTIRE next K-tile (8 loads/thr) at tile top, wait vmcnt(8)
//     -> each load has a full K-tile (~2.5k cyc) of cover, never drains to 0
//   - gray-coded quadrants (0,0)(0,1)(1,1)(1,0), af held across phases:
//     28 ds_read_b128/wave/tile instead of 48 (LDS was over the MFMA floor)
//   - 2 barriers/tile instead of 8
// Staging + epilogue byte-identical to round 2 (correctness-proven).
__global__ __launch_bounds__(512, 2) void gemm1_kernel(
    const unsigned short* __restrict__ A, const unsigned short* __restrict__ Bt,
    unsigned short* __restrict__ qo, unsigned short* __restrict__ ko,
    unsigned short* __restrict__ vo) {
  __shared__ unsigned short As[2][256 * 64];  // 32KB per buffer
  __shared__ unsigned short Bs[2][256 * 64];  // 32KB per buffer
  const int tid = threadIdx.x;
  const int wid = tid >> 6, lane = tid & 63;
  const int quad = lane >> 4, l16 = lane & 15;
  const int wm = (wid >> 2) * 128, wn = (wid & 3) * 64;

  // XCD-aware bijective swizzle over 192 blocks (192 % 8 == 0)
  const int id = blockIdx.x;
  const int swz = (id & 7) * 24 + (id >> 3);
  const int mb = swz / 12, nb = swz % 12;
  const int m0 = mb * 256, n0 = nb * 256;

  f32x4 acc[8][4] = {};

  // prologue: stage K-tile 0 into buffer 0 (8 loads/thread, left in flight)
  stage_tile(A, Bt, m0, n0, 0, &As[0][0], &Bs[0][0], tid);

  for (int kt = 0; kt < 16; kt++) {
    const int cur = kt & 1;
    const unsigned short* as = &As[cur][0];
    const unsigned short* bs = &Bs[cur][0];

    // all waves done reading buffer cur^1 (computed on it last tile)
    __builtin_amdgcn_s_barrier();
    if (kt < 15) {
      stage_tile(A, Bt, m0, n0, (kt + 1) * 64, &As[cur ^ 1][0], &Bs[cur ^ 1][0], tid);
      // wait for tile kt's 8 loads (issued a full tile ago); keep 8 in flight
      asm volatile("s_waitcnt vmcnt(8)" ::: "memory");
    } else {
      asm volatile("s_waitcnt vmcnt(0)" ::: "memory");
    }
    __builtin_amdgcn_s_barrier();   // buffer cur resident for ALL waves
    __builtin_amdgcn_sched_barrier(0);

    bf16x8 af[4][2], bfr[2][2];
    load_a4<0>(af, as, wm, l16, quad);
    load_b2<0>(bfr, bs, wn, l16, quad);
    mfma_quad<0, 0>(acc, af, bfr);
    load_b2<1>(bfr, bs, wn, l16, quad);
    mfma_quad<0, 1>(acc, af, bfr);
    load_a4<1>(af, as, wm, l16, quad);
    mfma_quad<1, 1>(acc, af, bfr);
    load_b2<0>(bfr, bs, wn, l16, quad);
    mfma_quad<1, 0>(acc, af, bfr);
  }

  // epilogue: C/D layout col=l16, row=quad*4+r (m89/m91-verified).
  // n0 is a multiple of 256 -> tile entirely within one of q/k/v (1024 each);
  // per-wave 64 cols = exactly one head.
  const int part = n0 >> 10;
  const int hh = ((n0 + wn) >> 6) & 15;
#pragma unroll
  for (int mi8 = 0; mi8 < 8; mi8++) {
#pragma unroll
    for (int r = 0; r < 4; r++) {
      const int m = m0 + wm + mi8 * 16 + quad * 4 + r;
      const int b = m >> 11, t = m & 2047;
#pragma unroll
      for (int ni = 0; ni < 4; ni++) {
        const int d = ni * 16 + l16;
        float val = acc[mi8][ni][r];
        if (part == 0) val *= QSCALE;   // fold softmax scale into Q (fp32, free)
        const unsigned short bv = f2bf(val);
        if (part == 0)
          qo[((size_t)(b * H_ + hh) * T_ + t) * D_ + d] = bv;
        else if (part == 1)
          ko[((size_t)(b * H_ + hh) * T_ + t) * D_ + d] = bv;
        else
          vo[((size_t)(b * H_ + hh) * D_ + d) * T_ + t] = bv;  // V pre-transposed [B,H,D,T]
      }
    }
  }
}

// ---------------- GEMM2: 512-thr split-K-in-block (r12) ----------------------
__global__ __launch_bounds__(512) void gemm2_kernel(
    const unsigned short* __restrict__ A, const unsigned short* __restrict__ Bt,
    float* __restrict__ fo) {
  __shared__ unsigned short As[2][128 * 64];  // 2 x 16KB, chunk-swizzled
  __shared__ unsigned short Bs[2][64 * 64];   // 2 x 8KB, chunk-swizzled
  const int tid = threadIdx.x;
  const int wave = tid >> 6, lane = tid & 63;
  const int quad = lane >> 4, l16 = lane & 15;
  const int grp = wave >> 2, w4 = wave & 3;
  const int wm = (w4 >> 1) * 64, wn = (w4 & 1) * 32;
  const int m0 = blockIdx.y * 128, n0 = blockIdx.x * 64;
  const int gtid = tid & 255;   // group-local thread id

  f32x4 acc[4][2] = {};
  const int kbase = grp * 512;
  unsigned short* Asg = &As[grp][0];
  unsigned short* Bsg = &Bs[grp][0];

  for (int kk = 0; kk < 512; kk += 64) {
    const int k = kbase + kk;
    __syncthreads();
#pragma unroll
    for (int i = 0; i < 4; i++) {
      const int s = gtid + 256 * i;
      const int row = s >> 3, ch = s & 7;
      gld16(A + (size_t)(m0 + row) * 1024 + k + ((ch ^ (row & 7)) * 8), Asg + s * 8);
    }
#pragma unroll
    for (int i = 0; i < 2; i++) {
      const int s = gtid + 256 * i;
      const int row = s >> 3, ch = s & 7;
      gld16(Bt + (size_t)(n0 + row) * 1024 + k + ((ch ^ (row & 7)) * 8), Bsg + s * 8);
    }
    __syncthreads();
#pragma unroll
    for (int sub = 0; sub < 2; sub++) {
      bf16x8 af[4], bfr[2];
#pragma unroll
      for (int mi = 0; mi < 4; mi++) {
        const int row = wm + mi * 16 + l16;
        af[mi] = *(const bf16x8*)(Asg + row * 64 + (((sub * 4 + quad) ^ (row & 7)) * 8));
      }
#pragma unroll
      for (int ni = 0; ni < 2; ni++) {
        const int row = wn + ni * 16 + l16;
        bfr[ni] = *(const bf16x8*)(Bsg + row * 64 + (((sub * 4 + quad) ^ (row & 7)) * 8));
      }
#pragma unroll
      for (int mi = 0; mi < 4; mi++)
#pragma unroll
        for (int ni = 0; ni < 2; ni++)
          acc[mi][ni] = __builtin_amdgcn_mfma_f32_16x16x32_bf16(af[mi], bfr[ni], acc[mi][ni], 0, 0, 0);
    }
  }

  // combine: group 1 -> LDS (reuse As, 32KB), group 0 adds + stores
  __syncthreads();
  float* comb = (float*)&As[0][0];
  if (grp == 1) {
#pragma unroll
    for (int mi = 0; mi < 4; mi++)
#pragma unroll
      for (int ni = 0; ni < 2; ni++)
        *(f32x4*)(comb + ((w4 * 8 + mi * 2 + ni) * 256 + lane * 4)) = acc[mi][ni];
  }
  __syncthreads();
  if (grp == 0) {
#pragma unroll
    for (int mi = 0; mi < 4; mi++) {
#pragma unroll
      for (int ni = 0; ni < 2; ni++) {
        f32x4 oth = *(const f32x4*)(comb + ((w4 * 8 + mi * 2 + ni) * 256 + lane * 4));
        f32x4 v = acc[mi][ni] + oth;
#pragma unroll
        for (int r = 0; r < 4; r++) {
          const int m = m0 + wm + mi * 16 + quad * 4 + r;
          fo[(size_t)m * 1024 + n0 + wn + ni * 16 + l16] = v[r];
        }
      }
    }
  }
}

// ---------------- flash attention: block staging + split-K + S^T softmax ------
// (r10 config: XCD-local bh = bid&31, longest chunks first — unchanged)
__global__ __launch_bounds__(256) void attn_kernel(
    const unsigned short* __restrict__ qb, const unsigned short* __restrict__ kb,
    const unsigned short* __restrict__ vb, unsigned short* __restrict__ yb,
    unsigned short* __restrict__ po, float* __restrict__ pl) {
  const int tid = threadIdx.x;
  const int wave = tid >> 6, lane = tid & 63;
  const int quad = lane >> 4, l16 = lane & 15;

  const int bid = blockIdx.x;
  const int bh = bid & 31;          // XCD-local: all 63 blocks of bh on one XCD
  const int u = 62 - (bid >> 5);    // longest chunks first
  int qs, c, nch;
  if (u < 11) { qs = u; c = 0; nch = 1; }
  else if (u < 33) { int v = u - 11; qs = 11 + (v >> 1); c = v & 1; nch = 2; }
  else { int v = u - 33; qs = 22 + v / 3; c = v % 3; nch = 3; }
  const int nt = qs + 1;
  const int j0 = c * nt / nch, j1 = (c + 1) * nt / nch;
  const int b = bh >> 4, h = bh & 15;

  __shared__ unsigned short Ks[64 * 64];     // [s][d], chunk-swizzled
  __shared__ unsigned short Vt[64 * 64];     // [d][s], chunk-swizzled
  __shared__ unsigned short Ps[4 * 16 * 68]; // per-wave P [q][s], stride 68
  unsigned short* Pw = Ps + wave * 16 * 68;

  const unsigned short* Qg = qb + (size_t)bh * T_ * D_;
  const unsigned short* Kg = kb + (size_t)bh * T_ * D_;
  const unsigned short* Vg = vb + (size_t)bh * D_ * T_;

  // Q fragment (B-operand: n=q=l16, k=d=quad*8+j)
  const unsigned short* qp = Qg + (size_t)(qs * 64 + wave * 16 + l16) * D_ + quad * 8;
  bf16x8 qf0 = *(const bf16x8*)qp, qf1 = *(const bf16x8*)(qp + 32);

  f32x4 o[4] = {};
  float lacc = 0.f;
  const int qglob = qs * 64 + wave * 16 + l16;   // this lane's q (S^T: col=l16)
  const int sloc_base = quad * 4;                // s-local row base (S^T: row=quad*4+r)

  const int trow = tid >> 3, tch = tid & 7;

  for (int jt = j0; jt < j1; jt++) {
    const int s0 = jt * 64;
    __syncthreads();
    {
      const int r0 = trow, r1 = trow + 32;
      gld16(Kg + (size_t)(s0 + r0) * D_ + ((tch ^ (r0 & 7)) * 8), Ks + r0 * 64 + tch * 8);
      gld16(Kg + (size_t)(s0 + r1) * D_ + ((tch ^ (r1 & 7)) * 8), Ks + r1 * 64 + tch * 8);
      gld16(Vg + (size_t)r0 * T_ + s0 + ((tch ^ (r0 & 7)) * 8), Vt + r0 * 64 + tch * 8);
      gld16(Vg + (size_t)r1 * T_ + s0 + ((tch ^ (r1 & 7)) * 8), Vt + r1 * 64 + tch * 8);
    }
    __syncthreads();

    // S^T = K Q^T : K as A-operand, Q as B-operand.
    // C-layout of s[mi]: row = s-local = mi*16+quad*4+r, col = q = l16.
    f32x4 s[4];
#pragma unroll
    for (int mi = 0; mi < 4; mi++) {
      const int row = mi * 16 + l16, sw = row & 7;
      bf16x8 kf0 = *(const bf16x8*)(Ks + row * 64 + ((quad ^ sw) * 8));
      bf16x8 kf1 = *(const bf16x8*)(Ks + row * 64 + (((quad + 4) ^ sw) * 8));
      f32x4 z = {0.f, 0.f, 0.f, 0.f};
      z = __builtin_amdgcn_mfma_f32_16x16x32_bf16(kf0, qf0, z, 0, 0, 0);
      s[mi] = __builtin_amdgcn_mfma_f32_16x16x32_bf16(kf1, qf1, z, 0, 0, 0);
    }

    if (jt == qs) {  // uniform diag branch: mask s > q
#pragma unroll
      for (int mi = 0; mi < 4; mi++)
#pragma unroll
        for (int r = 0; r < 4; r++) {
          float p = EXP2(s[mi][r]);
          p = (s0 + mi * 16 + sloc_base + r > qglob) ? 0.f : p;
          s[mi][r] = p;
          lacc += p;
        }
    } else {
#pragma unroll
      for (int mi = 0; mi < 4; mi++)
#pragma unroll
        for (int r = 0; r < 4; r++) {
          float p = EXP2(s[mi][r]);
          s[mi][r] = p;
          lacc += p;
        }
    }

    // P -> LDS [q=l16][s], packed dwords
#pragma unroll
    for (int mi = 0; mi < 4; mi++) {
      unsigned d0 = pack_bf2(s[mi][0], s[mi][1]);
      unsigned d1 = pack_bf2(s[mi][2], s[mi][3]);
      *(uint2*)(Pw + l16 * 68 + mi * 16 + quad * 4) = make_uint2(d0, d1);
    }

    // O += P V : P as A-operand (m=q=l16, k=s), V^T as B-operand
#pragma unroll
    for (int kk = 0; kk < 2; kk++) {
      bf16x8 pf = *(const bf16x8*)(Pw + l16 * 68 + kk * 32 + quad * 8);
#pragma unroll
      for (int ni = 0; ni < 4; ni++) {
        const int row = ni * 16 + l16, sw = row & 7;
        bf16x8 vf = *(const bf16x8*)(Vt + row * 64 + (((kk * 4 + quad) ^ sw) * 8));
        o[ni] = __builtin_amdgcn_mfma_f32_16x16x32_bf16(pf, vf, o[ni], 0, 0, 0);
      }
    }
  }

  // l: sum across the 4 lanes sharing l16 (quads), then fetch per-row values
  lacc += __shfl_xor(lacc, 16, 64);
  lacc += __shfl_xor(lacc, 32, 64);
  float lr[4];
#pragma unroll
  for (int r = 0; r < 4; r++) lr[r] = __shfl(lacc, quad * 4 + r, 16);  // l for q-row quad*4+r

  if (nch == 1) {
#pragma unroll
    for (int r = 0; r < 4; r++) {
      float inv = 1.0f / lr[r];
      int tq = qs * 64 + wave * 16 + quad * 4 + r;
#pragma unroll
      for (int ni = 0; ni < 4; ni++)
        yb[((size_t)(b * T_ + tq)) * 1024 + h * 64 + ni * 16 + l16] = f2bf(o[ni][r] * inv);
    }
  } else {
    const int slot = 52 * bh + ((qs <= 21) ? ((qs - 11) * 2 + c) : (22 + (qs - 22) * 3 + c));
    unsigned short* pob = po + (size_t)slot * 4096;
#pragma unroll
    for (int r = 0; r < 4; r++) {
      const int row64 = wave * 16 + quad * 4 + r;
#pragma unroll
      for (int ni = 0; ni < 4; ni++)
        pob[row64 * 64 + ni * 16 + l16] = f2bf(o[ni][r]);
      if (l16 == 0) pl[slot * 64 + row64] = lr[r];
    }
  }
}

// ---------------- split-K reduce: rows of strips qs>=11 ----------------
__global__ __launch_bounds__(256) void reduce_kernel(
    const unsigned short* __restrict__ po, const float* __restrict__ pl,
    unsigned short* __restrict__ yb) {
  int idx = blockIdx.x * 256 + threadIdx.x;
  int bh = idx / 21504;          // 1344 rows * 16 colgroups
  int rem = idx - bh * 21504;
  int rr = rem >> 4, cg = rem & 15;
  int qs = 11 + (rr >> 6), row64 = rr & 63;
  int base, nch;
  if (qs <= 21) { base = (qs - 11) * 2; nch = 2; }
  else { base = 22 + (qs - 22) * 3; nch = 3; }
  int b = bh >> 4, h = bh & 15;
  float a0 = 0.f, a1 = 0.f, a2 = 0.f, a3 = 0.f, l = 0.f;
  for (int cc = 0; cc < nch; cc++) {
    int slot = 52 * bh + base + cc;
    const unsigned short* p = po + (size_t)slot * 4096 + row64 * 64 + cg * 4;
    ushort4 uv = *(const ushort4*)p;
    a0 += bf2f(uv.x); a1 += bf2f(uv.y); a2 += bf2f(uv.z); a3 += bf2f(uv.w);
    l += pl[slot * 64 + row64];
  }
  float inv = 1.0f / l;
  int tq = qs * 64 + row64;
  ushort4 w;
  w.x = f2bf(a0 * inv); w.y = f2bf(a1 * inv); w.z = f2bf(a2 * inv); w.w = f2bf(a3 * inv);
  *(ushort4*)(yb + ((size_t)(b * T_ + tq)) * 1024 + h * 64 + cg * 4) = w;
}

// ---------------- launch ----------------
extern "C" void kernel_launch(void* const* d_in, const int* in_sizes, int n_in,
                              void* d_out, int out_size, void* d_ws, size_t ws_size,
                              hipStream_t stream) {
  const float* x = (const float*)d_in[0];       // [B,T,C]
  const float* w_qkv = (const float*)d_in[1];   // [C,3C]
  const float* w_proj = (const float*)d_in[2];  // [C,C]
  float* out = (float*)d_out;                   // [B,T,C] fp32

  // ws layout (shorts). po aliases wqkvT (dead after GEMM1). ~49.7 MB total.
  unsigned short* xb = (unsigned short*)d_ws;                 // 4.19M
  unsigned short* wprojT = xb + (size_t)BT_ * C_;             // 1.05M
  unsigned short* qb = wprojT + (size_t)C_ * C_;              // 4.19M
  unsigned short* kb = qb + (size_t)B_ * H_ * T_ * D_;        // 4.19M
  unsigned short* vb = kb + (size_t)B_ * H_ * T_ * D_;        // 4.19M
  unsigned short* wqkvT = vb + (size_t)B_ * H_ * T_ * D_;     // 3.15M
  unsigned short* po = wqkvT;                                 // 1664 slots * 4096 = 6.82M
  float* pl = (float*)(po + (size_t)1664 * 4096);             // 106K fp32
  unsigned short* yb = xb;  // reuse (x dead after GEMM1)

  prep_kernel<<<dim3(8192), 256, 0, stream>>>(x, xb, w_qkv, wqkvT, w_proj, wprojT);

  gemm1_kernel<<<dim3(192), 512, 0, stream>>>(xb, wqkvT, qb, kb, vb);
  attn_kernel<<<dim3(32 * 63), 256, 0, stream>>>(qb, kb, vb, yb, po, pl);
  reduce_kernel<<<dim3(2688), 256, 0, stream>>>(po, pl, yb);
  gemm2_kernel<<<dim3(C_ / 64, BT_ / 128), 512, 0, stream>>>(yb, wprojT, out);
}

// Round 4
// 190.956 us; speedup vs baseline: 1.1296x; 1.0784x over previous
//
#include <hip/hip_runtime.h>
#include <stdint.h>

#define LOG2E 1.4426950408889634f
#define QSCALE 0.18033688011112042f  // 0.125 * log2(e), folded into Q at GEMM1

typedef __attribute__((ext_vector_type(8))) short bf16x8;
typedef __attribute__((ext_vector_type(4))) float f32x4;
typedef __attribute__((ext_vector_type(8))) unsigned short u16x8;

#define B_ 2
#define T_ 2048
#define C_ 1024
#define H_ 16
#define D_ 64
#define BT_ 4096
#define N3_ 3072

#if __has_builtin(__builtin_amdgcn_exp2f)
#define EXP2(x) __builtin_amdgcn_exp2f(x)   // raw v_exp_f32 (inputs bounded, no denorm path)
#else
#define EXP2(x) exp2f(x)
#endif

__device__ __forceinline__ unsigned short f2bf(float f) {
  union { float f; unsigned u; } x; x.f = f;
  return (unsigned short)((x.u + 0x7fffu + ((x.u >> 16) & 1u)) >> 16);
}
__device__ __forceinline__ float bf2f(unsigned short u) {
  union { unsigned u; float f; } x; x.u = ((unsigned)u) << 16;
  return x.f;
}
__device__ __forceinline__ unsigned f2u(float f) {
  union { float f; unsigned u; } x; x.f = f; return x.u;
}
// pack two f32 -> dword of 2 bf16 (low short = a, high = b), round-nearest-away
__device__ __forceinline__ unsigned pack_bf2(float a, float b) {
  return __builtin_amdgcn_perm(f2u(b) + 0x8000u, f2u(a) + 0x8000u, 0x07060302u);
}

// async global->LDS 16B (m97 pattern). LDS dest must be wave-uniform base +
// lane*16 — all call sites below keep lds addr == linear(slot)*16B.
__device__ __forceinline__ void gld16(const unsigned short* g, unsigned short* l) {
  __builtin_amdgcn_global_load_lds(
      (const __attribute__((address_space(1))) unsigned int*)g,
      (__attribute__((address_space(3))) unsigned int*)l, 16, 0, 0);
}

// ---------------- prep (r11-proven): cvt + 2 transposes in one launch ---------
__device__ __forceinline__ void tr32(const float* __restrict__ in,
                                     unsigned short* __restrict__ out,
                                     int K, int N, int b, int nbx, int tid) {
  __shared__ unsigned short tile[32][33];
  const int bx = b % nbx, by = b / nbx;
  const int n0 = bx * 32, k0 = by * 32;
  const int tx = tid & 31, ty = (tid >> 5) * 4;
#pragma unroll
  for (int r = 0; r < 4; r++)
    tile[ty + r][tx] = f2bf(in[(size_t)(k0 + ty + r) * N + n0 + tx]);
  __syncthreads();
#pragma unroll
  for (int r = 0; r < 4; r++)
    out[(size_t)(n0 + ty + r) * K + k0 + tx] = tile[tx][ty + r];
}

__global__ __launch_bounds__(256) void prep_kernel(
    const float* __restrict__ x, unsigned short* __restrict__ xb,
    const float* __restrict__ wq, unsigned short* __restrict__ wqT,
    const float* __restrict__ wp, unsigned short* __restrict__ wpT) {
  const int bid = blockIdx.x, tid = threadIdx.x;
  if (bid < 4096) {
    int i = (bid * 256 + tid) * 4;
    float4 v = *(const float4*)(x + i);
    ushort4 o;
    o.x = f2bf(v.x); o.y = f2bf(v.y); o.z = f2bf(v.z); o.w = f2bf(v.w);
    *(ushort4*)(xb + i) = o;
  } else if (bid < 4096 + 3072) {
    tr32(wq, wqT, 1024, 3072, bid - 4096, 96, tid);
  } else {
    tr32(wp, wpT, 1024, 1024, bid - 7168, 32, tid);
  }
}

// ---------------- GEMM1 (r10 revert — proven 528 TF, 6 blocks/CU) ------------
// Rounds 1-3 postmortem: 128x128 (r1), 8-phase 256^2 (r2), coarse-prefetch
// 256^2 (r3) ALL regressed vs this 128x64 2-phase structure: on this shape
// (K=1024, 16 K-steps) perf tracks co-residency (6 blocks/CU -> 49us;
// 3 -> 62; 1 -> 64-79). Keep the high-occupancy known-good body.
// MODE 0: scatter-write q*QSCALE [B,H,T,D], k [B,H,T,D], v [B,H,D,T] bf16
// MODE 1: write fp32 out [m][n] (N=1024)
template <int MODE>
__global__ __launch_bounds__(256) void gemm_kernel(
    const unsigned short* __restrict__ A, const unsigned short* __restrict__ Bt,
    unsigned short* __restrict__ qo, unsigned short* __restrict__ ko,
    unsigned short* __restrict__ vo, float* __restrict__ fo) {
  __shared__ unsigned short As[128 * 64];   // [row][64], chunk-swizzled
  __shared__ unsigned short Bs[64 * 64];    // [row][64], chunk-swizzled
  const int tid = threadIdx.x;
  const int wave = tid >> 6, lane = tid & 63;
  const int quad = lane >> 4, l16 = lane & 15;
  const int wm = (wave >> 1) * 64, wn = (wave & 1) * 32;
  const int m0 = blockIdx.y * 128, n0 = blockIdx.x * 64;

  f32x4 acc[4][2] = {};

  for (int k = 0; k < 1024; k += 64) {
    __syncthreads();
#pragma unroll
    for (int i = 0; i < 4; i++) {
      const int s = tid + 256 * i;
      const int row = s >> 3, ch = s & 7;
      gld16(A + (size_t)(m0 + row) * 1024 + k + ((ch ^ (row & 7)) * 8), As + s * 8);
    }
#pragma unroll
    for (int i = 0; i < 2; i++) {
      const int s = tid + 256 * i;
      const int row = s >> 3, ch = s & 7;
      gld16(Bt + (size_t)(n0 + row) * 1024 + k + ((ch ^ (row & 7)) * 8), Bs + s * 8);
    }
    __syncthreads();
#pragma unroll
    for (int sub = 0; sub < 2; sub++) {
      bf16x8 af[4], bfr[2];
#pragma unroll
      for (int mi = 0; mi < 4; mi++) {
        const int row = wm + mi * 16 + l16;
        af[mi] = *(const bf16x8*)(As + row * 64 + (((sub * 4 + quad) ^ (row & 7)) * 8));
      }
#pragma unroll
      for (int ni = 0; ni < 2; ni++) {
        const int row = wn + ni * 16 + l16;
        bfr[ni] = *(const bf16x8*)(Bs + row * 64 + (((sub * 4 + quad) ^ (row & 7)) * 8));
      }
#pragma unroll
      for (int mi = 0; mi < 4; mi++)
#pragma unroll
        for (int ni = 0; ni < 2; ni++)
          acc[mi][ni] = __builtin_amdgcn_mfma_f32_16x16x32_bf16(af[mi], bfr[ni], acc[mi][ni], 0, 0, 0);
    }
  }

  // epilogue: C/D layout col=l16, row=quad*4+r (m89/m91-verified)
  if (MODE == 0) {
    const int part = n0 >> 10;          // block-uniform
    const int hh = (n0 >> 6) & 15;      // block-uniform
#pragma unroll
    for (int mi = 0; mi < 4; mi++) {
#pragma unroll
      for (int r = 0; r < 4; r++) {
        const int m = m0 + wm + mi * 16 + quad * 4 + r;
        const int b = m >> 11, t = m & 2047;
#pragma unroll
        for (int ni = 0; ni < 2; ni++) {
          const int d = wn + ni * 16 + l16;
          float val = acc[mi][ni][r];
          if (part == 0) val *= QSCALE;   // fold softmax scale into Q (fp32, free)
          const unsigned short bv = f2bf(val);
          if (part == 0)
            qo[((size_t)(b * H_ + hh) * T_ + t) * D_ + d] = bv;
          else if (part == 1)
            ko[((size_t)(b * H_ + hh) * T_ + t) * D_ + d] = bv;
          else
            vo[((size_t)(b * H_ + hh) * D_ + d) * T_ + t] = bv;  // V pre-transposed [B,H,D,T]
        }
      }
    }
  } else {
#pragma unroll
    for (int mi = 0; mi < 4; mi++)
#pragma unroll
      for (int r = 0; r < 4; r++) {
        const int m = m0 + wm + mi * 16 + quad * 4 + r;
#pragma unroll
        for (int ni = 0; ni < 2; ni++)
          fo[(size_t)m * 1024 + n0 + wn + ni * 16 + l16] = acc[mi][ni][r];
      }
  }
}

// ---------------- GEMM2: 512-thr split-K-in-block (r12) ----------------------
__global__ __launch_bounds__(512) void gemm2_kernel(
    const unsigned short* __restrict__ A, const unsigned short* __restrict__ Bt,
    float* __restrict__ fo) {
  __shared__ unsigned short As[2][128 * 64];  // 2 x 16KB, chunk-swizzled
  __shared__ unsigned short Bs[2][64 * 64];   // 2 x 8KB, chunk-swizzled
  const int tid = threadIdx.x;
  const int wave = tid >> 6, lane = tid & 63;
  const int quad = lane >> 4, l16 = lane & 15;
  const int grp = wave >> 2, w4 = wave & 3;
  const int wm = (w4 >> 1) * 64, wn = (w4 & 1) * 32;
  const int m0 = blockIdx.y * 128, n0 = blockIdx.x * 64;
  const int gtid = tid & 255;   // group-local thread id

  f32x4 acc[4][2] = {};
  const int kbase = grp * 512;
  unsigned short* Asg = &As[grp][0];
  unsigned short* Bsg = &Bs[grp][0];

  for (int kk = 0; kk < 512; kk += 64) {
    const int k = kbase + kk;
    __syncthreads();
#pragma unroll
    for (int i = 0; i < 4; i++) {
      const int s = gtid + 256 * i;
      const int row = s >> 3, ch = s & 7;
      gld16(A + (size_t)(m0 + row) * 1024 + k + ((ch ^ (row & 7)) * 8), Asg + s * 8);
    }
#pragma unroll
    for (int i = 0; i < 2; i++) {
      const int s = gtid + 256 * i;
      const int row = s >> 3, ch = s & 7;
      gld16(Bt + (size_t)(n0 + row) * 1024 + k + ((ch ^ (row & 7)) * 8), Bsg + s * 8);
    }
    __syncthreads();
#pragma unroll
    for (int sub = 0; sub < 2; sub++) {
      bf16x8 af[4], bfr[2];
#pragma unroll
      for (int mi = 0; mi < 4; mi++) {
        const int row = wm + mi * 16 + l16;
        af[mi] = *(const bf16x8*)(Asg + row * 64 + (((sub * 4 + quad) ^ (row & 7)) * 8));
      }
#pragma unroll
      for (int ni = 0; ni < 2; ni++) {
        const int row = wn + ni * 16 + l16;
        bfr[ni] = *(const bf16x8*)(Bsg + row * 64 + (((sub * 4 + quad) ^ (row & 7)) * 8));
      }
#pragma unroll
      for (int mi = 0; mi < 4; mi++)
#pragma unroll
        for (int ni = 0; ni < 2; ni++)
          acc[mi][ni] = __builtin_amdgcn_mfma_f32_16x16x32_bf16(af[mi], bfr[ni], acc[mi][ni], 0, 0, 0);
    }
  }

  // combine: group 1 -> LDS (reuse As, 32KB), group 0 adds + stores
  __syncthreads();
  float* comb = (float*)&As[0][0];
  if (grp == 1) {
#pragma unroll
    for (int mi = 0; mi < 4; mi++)
#pragma unroll
      for (int ni = 0; ni < 2; ni++)
        *(f32x4*)(comb + ((w4 * 8 + mi * 2 + ni) * 256 + lane * 4)) = acc[mi][ni];
  }
  __syncthreads();
  if (grp == 0) {
#pragma unroll
    for (int mi = 0; mi < 4; mi++) {
#pragma unroll
      for (int ni = 0; ni < 2; ni++) {
        f32x4 oth = *(const f32x4*)(comb + ((w4 * 8 + mi * 2 + ni) * 256 + lane * 4));
        f32x4 v = acc[mi][ni] + oth;
#pragma unroll
        for (int r = 0; r < 4; r++) {
          const int m = m0 + wm + mi * 16 + quad * 4 + r;
          fo[(size_t)m * 1024 + n0 + wn + ni * 16 + l16] = v[r];
        }
      }
    }
  }
}

// ---------------- flash attention: dbuf K/V prefetch + split-K + S^T softmax --
// r4 change: double-buffered K/V staging (T14/m97 issue-early pattern).
// Old: barrier -> gld16 x4 -> barrier -> compute  (full L2 latency on the
// critical path every kv-tile, hidden only by co-resident blocks).
// New: ONE __syncthreads per tile (its vmcnt(0) drain waits for loads issued
// a full compute phase earlier), then issue tile jt+1 into the idle buffer,
// then compute tile jt. Overwrite-safe: prefetch targets buf^1 whose readers
// all finished before the barrier just crossed. LDS 24.5 -> 40.7 KB
// (3 blocks/CU instead of 6; stall now pipelined away instead of hidden).
__global__ __launch_bounds__(256) void attn_kernel(
    const unsigned short* __restrict__ qb, const unsigned short* __restrict__ kb,
    const unsigned short* __restrict__ vb, unsigned short* __restrict__ yb,
    unsigned short* __restrict__ po, float* __restrict__ pl) {
  const int tid = threadIdx.x;
  const int wave = tid >> 6, lane = tid & 63;
  const int quad = lane >> 4, l16 = lane & 15;

  const int bid = blockIdx.x;
  const int bh = bid & 31;          // XCD-local: all 63 blocks of bh on one XCD
  const int u = 62 - (bid >> 5);    // longest chunks first
  int qs, c, nch;
  if (u < 11) { qs = u; c = 0; nch = 1; }
  else if (u < 33) { int v = u - 11; qs = 11 + (v >> 1); c = v & 1; nch = 2; }
  else { int v = u - 33; qs = 22 + v / 3; c = v % 3; nch = 3; }
  const int nt = qs + 1;
  const int j0 = c * nt / nch, j1 = (c + 1) * nt / nch;
  const int b = bh >> 4, h = bh & 15;

  __shared__ unsigned short Ks[2][64 * 64];  // [s][d], chunk-swizzled, dbuf
  __shared__ unsigned short Vt[2][64 * 64];  // [d][s], chunk-swizzled, dbuf
  __shared__ unsigned short Ps[4 * 16 * 68]; // per-wave P [q][s], stride 68
  unsigned short* Pw = Ps + wave * 16 * 68;

  const unsigned short* Qg = qb + (size_t)bh * T_ * D_;
  const unsigned short* Kg = kb + (size_t)bh * T_ * D_;
  const unsigned short* Vg = vb + (size_t)bh * D_ * T_;

  // Q fragment (B-operand: n=q=l16, k=d=quad*8+j)
  const unsigned short* qp = Qg + (size_t)(qs * 64 + wave * 16 + l16) * D_ + quad * 8;
  bf16x8 qf0 = *(const bf16x8*)qp, qf1 = *(const bf16x8*)(qp + 32);

  f32x4 o[4] = {};
  float lacc = 0.f;
  const int qglob = qs * 64 + wave * 16 + l16;   // this lane's q (S^T: col=l16)
  const int sloc_base = quad * 4;                // s-local row base (S^T: row=quad*4+r)

  const int trow = tid >> 3, tch = tid & 7;
  const int r0 = trow, r1 = trow + 32;

  // stage kv-tile jtile into buffer bf (4 gld16 / thread, 256 thr)
  auto stage_kv = [&](int jtile, int bf) {
    const int ss = jtile * 64;
    gld16(Kg + (size_t)(ss + r0) * D_ + ((tch ^ (r0 & 7)) * 8), &Ks[bf][0] + r0 * 64 + tch * 8);
    gld16(Kg + (size_t)(ss + r1) * D_ + ((tch ^ (r1 & 7)) * 8), &Ks[bf][0] + r1 * 64 + tch * 8);
    gld16(Vg + (size_t)r0 * T_ + ss + ((tch ^ (r0 & 7)) * 8), &Vt[bf][0] + r0 * 64 + tch * 8);
    gld16(Vg + (size_t)r1 * T_ + ss + ((tch ^ (r1 & 7)) * 8), &Vt[bf][0] + r1 * 64 + tch * 8);
  };

  // prologue: issue tile j0 into buffer 0 (left in flight)
  stage_kv(j0, 0);

  for (int jt = j0; jt < j1; jt++) {
    const int s0 = jt * 64;
    const int cur = (jt - j0) & 1;
    // drains vmcnt(0): tile jt resident; all waves past reads of buf cur^1
    __syncthreads();
    if (jt + 1 < j1) stage_kv(jt + 1, cur ^ 1);
    const unsigned short* Ksb = &Ks[cur][0];
    const unsigned short* Vtb = &Vt[cur][0];

    // S^T = K Q^T : K as A-operand, Q as B-operand.
    // C-layout of s[mi]: row = s-local = mi*16+quad*4+r, col = q = l16.
    f32x4 s[4];
#pragma unroll
    for (int mi = 0; mi < 4; mi++) {
      const int row = mi * 16 + l16, sw = row & 7;
      bf16x8 kf0 = *(const bf16x8*)(Ksb + row * 64 + ((quad ^ sw) * 8));
      bf16x8 kf1 = *(const bf16x8*)(Ksb + row * 64 + (((quad + 4) ^ sw) * 8));
      f32x4 z = {0.f, 0.f, 0.f, 0.f};
      z = __builtin_amdgcn_mfma_f32_16x16x32_bf16(kf0, qf0, z, 0, 0, 0);
      s[mi] = __builtin_amdgcn_mfma_f32_16x16x32_bf16(kf1, qf1, z, 0, 0, 0);
    }

    if (jt == qs) {  // uniform diag branch: mask s > q
#pragma unroll
      for (int mi = 0; mi < 4; mi++)
#pragma unroll
        for (int r = 0; r < 4; r++) {
          float p = EXP2(s[mi][r]);
          p = (s0 + mi * 16 + sloc_base + r > qglob) ? 0.f : p;
          s[mi][r] = p;
          lacc += p;
        }
    } else {
#pragma unroll
      for (int mi = 0; mi < 4; mi++)
#pragma unroll
        for (int r = 0; r < 4; r++) {
          float p = EXP2(s[mi][r]);
          s[mi][r] = p;
          lacc += p;
        }
    }

    // P -> LDS [q=l16][s], packed dwords
#pragma unroll
    for (int mi = 0; mi < 4; mi++) {
      unsigned d0 = pack_bf2(s[mi][0], s[mi][1]);
      unsigned d1 = pack_bf2(s[mi][2], s[mi][3]);
      *(uint2*)(Pw + l16 * 68 + mi * 16 + quad * 4) = make_uint2(d0, d1);
    }

    // O += P V : P as A-operand (m=q=l16, k=s), V^T as B-operand
#pragma unroll
    for (int kk = 0; kk < 2; kk++) {
      bf16x8 pf = *(const bf16x8*)(Pw + l16 * 68 + kk * 32 + quad * 8);
#pragma unroll
      for (int ni = 0; ni < 4; ni++) {
        const int row = ni * 16 + l16, sw = row & 7;
        bf16x8 vf = *(const bf16x8*)(Vtb + row * 64 + (((kk * 4 + quad) ^ sw) * 8));
        o[ni] = __builtin_amdgcn_mfma_f32_16x16x32_bf16(pf, vf, o[ni], 0, 0, 0);
      }
    }
  }

  // l: sum across the 4 lanes sharing l16 (quads), then fetch per-row values
  lacc += __shfl_xor(lacc, 16, 64);
  lacc += __shfl_xor(lacc, 32, 64);
  float lr[4];
#pragma unroll
  for (int r = 0; r < 4; r++) lr[r] = __shfl(lacc, quad * 4 + r, 16);  // l for q-row quad*4+r

  if (nch == 1) {
#pragma unroll
    for (int r = 0; r < 4; r++) {
      float inv = 1.0f / lr[r];
      int tq = qs * 64 + wave * 16 + quad * 4 + r;
#pragma unroll
      for (int ni = 0; ni < 4; ni++)
        yb[((size_t)(b * T_ + tq)) * 1024 + h * 64 + ni * 16 + l16] = f2bf(o[ni][r] * inv);
    }
  } else {
    const int slot = 52 * bh + ((qs <= 21) ? ((qs - 11) * 2 + c) : (22 + (qs - 22) * 3 + c));
    unsigned short* pob = po + (size_t)slot * 4096;
#pragma unroll
    for (int r = 0; r < 4; r++) {
      const int row64 = wave * 16 + quad * 4 + r;
#pragma unroll
      for (int ni = 0; ni < 4; ni++)
        pob[row64 * 64 + ni * 16 + l16] = f2bf(o[ni][r]);
      if (l16 == 0) pl[slot * 64 + row64] = lr[r];
    }
  }
}

// ---------------- split-K reduce: rows of strips qs>=11 ----------------
__global__ __launch_bounds__(256) void reduce_kernel(
    const unsigned short* __restrict__ po, const float* __restrict__ pl,
    unsigned short* __restrict__ yb) {
  int idx = blockIdx.x * 256 + threadIdx.x;
  int bh = idx / 21504;          // 1344 rows * 16 colgroups
  int rem = idx - bh * 21504;
  int rr = rem >> 4, cg = rem & 15;
  int qs = 11 + (rr >> 6), row64 = rr & 63;
  int base, nch;
  if (qs <= 21) { base = (qs - 11) * 2; nch = 2; }
  else { base = 22 + (qs - 22) * 3; nch = 3; }
  int b = bh >> 4, h = bh & 15;
  float a0 = 0.f, a1 = 0.f, a2 = 0.f, a3 = 0.f, l = 0.f;
  for (int cc = 0; cc < nch; cc++) {
    int slot = 52 * bh + base + cc;
    const unsigned short* p = po + (size_t)slot * 4096 + row64 * 64 + cg * 4;
    ushort4 uv = *(const ushort4*)p;
    a0 += bf2f(uv.x); a1 += bf2f(uv.y); a2 += bf2f(uv.z); a3 += bf2f(uv.w);
    l += pl[slot * 64 + row64];
  }
  float inv = 1.0f / l;
  int tq = qs * 64 + row64;
  ushort4 w;
  w.x = f2bf(a0 * inv); w.y = f2bf(a1 * inv); w.z = f2bf(a2 * inv); w.w = f2bf(a3 * inv);
  *(ushort4*)(yb + ((size_t)(b * T_ + tq)) * 1024 + h * 64 + cg * 4) = w;
}

// ---------------- launch ----------------
extern "C" void kernel_launch(void* const* d_in, const int* in_sizes, int n_in,
                              void* d_out, int out_size, void* d_ws, size_t ws_size,
                              hipStream_t stream) {
  const float* x = (const float*)d_in[0];       // [B,T,C]
  const float* w_qkv = (const float*)d_in[1];   // [C,3C]
  const float* w_proj = (const float*)d_in[2];  // [C,C]
  float* out = (float*)d_out;                   // [B,T,C] fp32

  // ws layout (shorts). po aliases wqkvT (dead after GEMM1). ~49.7 MB total.
  unsigned short* xb = (unsigned short*)d_ws;                 // 4.19M
  unsigned short* wprojT = xb + (size_t)BT_ * C_;             // 1.05M
  unsigned short* qb = wprojT + (size_t)C_ * C_;              // 4.19M
  unsigned short* kb = qb + (size_t)B_ * H_ * T_ * D_;        // 4.19M
  unsigned short* vb = kb + (size_t)B_ * H_ * T_ * D_;        // 4.19M
  unsigned short* wqkvT = vb + (size_t)B_ * H_ * T_ * D_;     // 3.15M
  unsigned short* po = wqkvT;                                 // 1664 slots * 4096 = 6.82M
  float* pl = (float*)(po + (size_t)1664 * 4096);             // 106K fp32
  unsigned short* yb = xb;  // reuse (x dead after GEMM1)

  prep_kernel<<<dim3(8192), 256, 0, stream>>>(x, xb, w_qkv, wqkvT, w_proj, wprojT);

  gemm_kernel<0><<<dim3(N3_ / 64, BT_ / 128), 256, 0, stream>>>(xb, wqkvT, qb, kb, vb, nullptr);
  attn_kernel<<<dim3(32 * 63), 256, 0, stream>>>(qb, kb, vb, yb, po, pl);
  reduce_kernel<<<dim3(2688), 256, 0, stream>>>(po, pl, yb);
  gemm2_kernel<<<dim3(C_ / 64, BT_ / 128), 512, 0, stream>>>(yb, wprojT, out);
}

// Round 5
// 187.724 us; speedup vs baseline: 1.1490x; 1.0172x over previous
//
#include <hip/hip_runtime.h>
#include <stdint.h>

#define LOG2E 1.4426950408889634f
#define QSCALE 0.18033688011112042f  // 0.125 * log2(e), folded into Q at GEMM1

typedef __attribute__((ext_vector_type(8))) short bf16x8;
typedef __attribute__((ext_vector_type(4))) float f32x4;
typedef __attribute__((ext_vector_type(8))) unsigned short u16x8;

#define B_ 2
#define T_ 2048
#define C_ 1024
#define H_ 16
#define D_ 64
#define BT_ 4096
#define N3_ 3072

#if __has_builtin(__builtin_amdgcn_exp2f)
#define EXP2(x) __builtin_amdgcn_exp2f(x)   // raw v_exp_f32 (inputs bounded, no denorm path)
#else
#define EXP2(x) exp2f(x)
#endif

__device__ __forceinline__ unsigned short f2bf(float f) {
  union { float f; unsigned u; } x; x.f = f;
  return (unsigned short)((x.u + 0x7fffu + ((x.u >> 16) & 1u)) >> 16);
}
__device__ __forceinline__ float bf2f(unsigned short u) {
  union { unsigned u; float f; } x; x.u = ((unsigned)u) << 16;
  return x.f;
}
__device__ __forceinline__ unsigned f2u(float f) {
  union { float f; unsigned u; } x; x.f = f; return x.u;
}
// pack two f32 -> dword of 2 bf16 (low short = a, high = b), round-nearest-away
__device__ __forceinline__ unsigned pack_bf2(float a, float b) {
  return __builtin_amdgcn_perm(f2u(b) + 0x8000u, f2u(a) + 0x8000u, 0x07060302u);
}

// async global->LDS 16B (m97 pattern). LDS dest must be wave-uniform base +
// lane*16 — all call sites below keep lds addr == linear(slot)*16B.
__device__ __forceinline__ void gld16(const unsigned short* g, unsigned short* l) {
  __builtin_amdgcn_global_load_lds(
      (const __attribute__((address_space(1))) unsigned int*)g,
      (__attribute__((address_space(3))) unsigned int*)l, 16, 0, 0);
}

// ---------------- prep (r11-proven): cvt + 2 transposes in one launch ---------
__device__ __forceinline__ void tr32(const float* __restrict__ in,
                                     unsigned short* __restrict__ out,
                                     int K, int N, int b, int nbx, int tid) {
  __shared__ unsigned short tile[32][33];
  const int bx = b % nbx, by = b / nbx;
  const int n0 = bx * 32, k0 = by * 32;
  const int tx = tid & 31, ty = (tid >> 5) * 4;
#pragma unroll
  for (int r = 0; r < 4; r++)
    tile[ty + r][tx] = f2bf(in[(size_t)(k0 + ty + r) * N + n0 + tx]);
  __syncthreads();
#pragma unroll
  for (int r = 0; r < 4; r++)
    out[(size_t)(n0 + ty + r) * K + k0 + tx] = tile[tx][ty + r];
}

__global__ __launch_bounds__(256) void prep_kernel(
    const float* __restrict__ x, unsigned short* __restrict__ xb,
    const float* __restrict__ wq, unsigned short* __restrict__ wqT,
    const float* __restrict__ wp, unsigned short* __restrict__ wpT) {
  const int bid = blockIdx.x, tid = threadIdx.x;
  if (bid < 4096) {
    int i = (bid * 256 + tid) * 4;
    float4 v = *(const float4*)(x + i);
    ushort4 o;
    o.x = f2bf(v.x); o.y = f2bf(v.y); o.z = f2bf(v.z); o.w = f2bf(v.w);
    *(ushort4*)(xb + i) = o;
  } else if (bid < 4096 + 3072) {
    tr32(wq, wqT, 1024, 3072, bid - 4096, 96, tid);
  } else {
    tr32(wp, wpT, 1024, 1024, bid - 7168, 32, tid);
  }
}

// ---------------- GEMM1 (r10 revert — proven 528 TF, 6 blocks/CU) ------------
// Rounds 1-3 postmortem: 128x128 (r1), 8-phase 256^2 (r2), coarse-prefetch
// 256^2 (r3) ALL regressed vs this 128x64 2-phase structure: on this shape
// perf tracks in-flight staging parallelism (blocks/CU). Keep known-good body.
// MODE 0: scatter-write q*QSCALE [B,H,T,D], k [B,H,T,D], v [B,H,D,T] bf16
// MODE 1: write fp32 out [m][n] (N=1024)
template <int MODE>
__global__ __launch_bounds__(256) void gemm_kernel(
    const unsigned short* __restrict__ A, const unsigned short* __restrict__ Bt,
    unsigned short* __restrict__ qo, unsigned short* __restrict__ ko,
    unsigned short* __restrict__ vo, float* __restrict__ fo) {
  __shared__ unsigned short As[128 * 64];   // [row][64], chunk-swizzled
  __shared__ unsigned short Bs[64 * 64];    // [row][64], chunk-swizzled
  const int tid = threadIdx.x;
  const int wave = tid >> 6, lane = tid & 63;
  const int quad = lane >> 4, l16 = lane & 15;
  const int wm = (wave >> 1) * 64, wn = (wave & 1) * 32;
  const int m0 = blockIdx.y * 128, n0 = blockIdx.x * 64;

  f32x4 acc[4][2] = {};

  for (int k = 0; k < 1024; k += 64) {
    __syncthreads();
#pragma unroll
    for (int i = 0; i < 4; i++) {
      const int s = tid + 256 * i;
      const int row = s >> 3, ch = s & 7;
      gld16(A + (size_t)(m0 + row) * 1024 + k + ((ch ^ (row & 7)) * 8), As + s * 8);
    }
#pragma unroll
    for (int i = 0; i < 2; i++) {
      const int s = tid + 256 * i;
      const int row = s >> 3, ch = s & 7;
      gld16(Bt + (size_t)(n0 + row) * 1024 + k + ((ch ^ (row & 7)) * 8), Bs + s * 8);
    }
    __syncthreads();
#pragma unroll
    for (int sub = 0; sub < 2; sub++) {
      bf16x8 af[4], bfr[2];
#pragma unroll
      for (int mi = 0; mi < 4; mi++) {
        const int row = wm + mi * 16 + l16;
        af[mi] = *(const bf16x8*)(As + row * 64 + (((sub * 4 + quad) ^ (row & 7)) * 8));
      }
#pragma unroll
      for (int ni = 0; ni < 2; ni++) {
        const int row = wn + ni * 16 + l16;
        bfr[ni] = *(const bf16x8*)(Bs + row * 64 + (((sub * 4 + quad) ^ (row & 7)) * 8));
      }
#pragma unroll
      for (int mi = 0; mi < 4; mi++)
#pragma unroll
        for (int ni = 0; ni < 2; ni++)
          acc[mi][ni] = __builtin_amdgcn_mfma_f32_16x16x32_bf16(af[mi], bfr[ni], acc[mi][ni], 0, 0, 0);
    }
  }

  // epilogue: C/D layout col=l16, row=quad*4+r (m89/m91-verified)
  if (MODE == 0) {
    const int part = n0 >> 10;          // block-uniform
    const int hh = (n0 >> 6) & 15;      // block-uniform
#pragma unroll
    for (int mi = 0; mi < 4; mi++) {
#pragma unroll
      for (int r = 0; r < 4; r++) {
        const int m = m0 + wm + mi * 16 + quad * 4 + r;
        const int b = m >> 11, t = m & 2047;
#pragma unroll
        for (int ni = 0; ni < 2; ni++) {
          const int d = wn + ni * 16 + l16;
          float val = acc[mi][ni][r];
          if (part == 0) val *= QSCALE;   // fold softmax scale into Q (fp32, free)
          const unsigned short bv = f2bf(val);
          if (part == 0)
            qo[((size_t)(b * H_ + hh) * T_ + t) * D_ + d] = bv;
          else if (part == 1)
            ko[((size_t)(b * H_ + hh) * T_ + t) * D_ + d] = bv;
          else
            vo[((size_t)(b * H_ + hh) * D_ + d) * T_ + t] = bv;  // V pre-transposed [B,H,D,T]
        }
      }
    }
  } else {
#pragma unroll
    for (int mi = 0; mi < 4; mi++)
#pragma unroll
      for (int r = 0; r < 4; r++) {
        const int m = m0 + wm + mi * 16 + quad * 4 + r;
#pragma unroll
        for (int ni = 0; ni < 2; ni++)
          fo[(size_t)m * 1024 + n0 + wn + ni * 16 + l16] = acc[mi][ni][r];
      }
  }
}

// ---------------- GEMM2: 64x64 tile, high-occupancy 2-phase (r5) -------------
// r4 analysis: gemm2 at 128x64/512-thr had only 512 blocks (~3/CU, 48KB LDS)
// -> achieved staging BW ~4 TB/s vs gemm1's ~12 TB/s (1536 blocks, 6/CU).
// Achieved BW tracks blocks-in-flight on this machine (r0-r3 data). Fix:
// 64x64 tile, 256 thr, 16KB LDS -> grid (16,64)=1024 blocks at ~8/CU capacity.
// Same proven 2-phase body; acc[2][2] per wave (wave-grid 2x2 of 32x32).
__global__ __launch_bounds__(256) void gemm2_kernel(
    const unsigned short* __restrict__ A, const unsigned short* __restrict__ Bt,
    float* __restrict__ fo) {
  __shared__ unsigned short As[64 * 64];   // 8KB, chunk-swizzled
  __shared__ unsigned short Bs[64 * 64];   // 8KB, chunk-swizzled
  const int tid = threadIdx.x;
  const int wave = tid >> 6, lane = tid & 63;
  const int quad = lane >> 4, l16 = lane & 15;
  const int wm = (wave >> 1) * 32, wn = (wave & 1) * 32;
  const int m0 = blockIdx.y * 64, n0 = blockIdx.x * 64;

  f32x4 acc[2][2] = {};

  for (int k = 0; k < 1024; k += 64) {
    __syncthreads();
#pragma unroll
    for (int i = 0; i < 2; i++) {
      const int s = tid + 256 * i;
      const int row = s >> 3, ch = s & 7;
      gld16(A + (size_t)(m0 + row) * 1024 + k + ((ch ^ (row & 7)) * 8), As + s * 8);
      gld16(Bt + (size_t)(n0 + row) * 1024 + k + ((ch ^ (row & 7)) * 8), Bs + s * 8);
    }
    __syncthreads();
#pragma unroll
    for (int sub = 0; sub < 2; sub++) {
      bf16x8 af[2], bfr[2];
#pragma unroll
      for (int mi = 0; mi < 2; mi++) {
        const int row = wm + mi * 16 + l16;
        af[mi] = *(const bf16x8*)(As + row * 64 + (((sub * 4 + quad) ^ (row & 7)) * 8));
      }
#pragma unroll
      for (int ni = 0; ni < 2; ni++) {
        const int row = wn + ni * 16 + l16;
        bfr[ni] = *(const bf16x8*)(Bs + row * 64 + (((sub * 4 + quad) ^ (row & 7)) * 8));
      }
#pragma unroll
      for (int mi = 0; mi < 2; mi++)
#pragma unroll
        for (int ni = 0; ni < 2; ni++)
          acc[mi][ni] = __builtin_amdgcn_mfma_f32_16x16x32_bf16(af[mi], bfr[ni], acc[mi][ni], 0, 0, 0);
    }
  }

  // epilogue: C/D layout col=l16, row=quad*4+r
#pragma unroll
  for (int mi = 0; mi < 2; mi++)
#pragma unroll
    for (int r = 0; r < 4; r++) {
      const int m = m0 + wm + mi * 16 + quad * 4 + r;
#pragma unroll
      for (int ni = 0; ni < 2; ni++)
        fo[(size_t)m * 1024 + n0 + wn + ni * 16 + l16] = acc[mi][ni][r];
    }
}

// ---------------- flash attention (r0 revert): block staging + split-K -------
// r4 dbuf prefetch REGRESSED (48 -> 54us): 41.5KB LDS halved co-residency and
// one compute phase didn't cover the load latency. Restore r0 single-buffer
// (24.5KB LDS, stall hidden by 6 co-resident blocks — same lesson as gemm1).
__global__ __launch_bounds__(256) void attn_kernel(
    const unsigned short* __restrict__ qb, const unsigned short* __restrict__ kb,
    const unsigned short* __restrict__ vb, unsigned short* __restrict__ yb,
    unsigned short* __restrict__ po, float* __restrict__ pl) {
  const int tid = threadIdx.x;
  const int wave = tid >> 6, lane = tid & 63;
  const int quad = lane >> 4, l16 = lane & 15;

  const int bid = blockIdx.x;
  const int bh = bid & 31;          // XCD-local: all 63 blocks of bh on one XCD
  const int u = 62 - (bid >> 5);    // longest chunks first
  int qs, c, nch;
  if (u < 11) { qs = u; c = 0; nch = 1; }
  else if (u < 33) { int v = u - 11; qs = 11 + (v >> 1); c = v & 1; nch = 2; }
  else { int v = u - 33; qs = 22 + v / 3; c = v % 3; nch = 3; }
  const int nt = qs + 1;
  const int j0 = c * nt / nch, j1 = (c + 1) * nt / nch;
  const int b = bh >> 4, h = bh & 15;

  __shared__ unsigned short Ks[64 * 64];     // [s][d], chunk-swizzled
  __shared__ unsigned short Vt[64 * 64];     // [d][s], chunk-swizzled
  __shared__ unsigned short Ps[4 * 16 * 68]; // per-wave P [q][s], stride 68
  unsigned short* Pw = Ps + wave * 16 * 68;

  const unsigned short* Qg = qb + (size_t)bh * T_ * D_;
  const unsigned short* Kg = kb + (size_t)bh * T_ * D_;
  const unsigned short* Vg = vb + (size_t)bh * D_ * T_;

  // Q fragment (B-operand: n=q=l16, k=d=quad*8+j)
  const unsigned short* qp = Qg + (size_t)(qs * 64 + wave * 16 + l16) * D_ + quad * 8;
  bf16x8 qf0 = *(const bf16x8*)qp, qf1 = *(const bf16x8*)(qp + 32);

  f32x4 o[4] = {};
  float lacc = 0.f;
  const int qglob = qs * 64 + wave * 16 + l16;   // this lane's q (S^T: col=l16)
  const int sloc_base = quad * 4;                // s-local row base (S^T: row=quad*4+r)

  const int trow = tid >> 3, tch = tid & 7;

  for (int jt = j0; jt < j1; jt++) {
    const int s0 = jt * 64;
    __syncthreads();
    {
      const int r0 = trow, r1 = trow + 32;
      gld16(Kg + (size_t)(s0 + r0) * D_ + ((tch ^ (r0 & 7)) * 8), Ks + r0 * 64 + tch * 8);
      gld16(Kg + (size_t)(s0 + r1) * D_ + ((tch ^ (r1 & 7)) * 8), Ks + r1 * 64 + tch * 8);
      gld16(Vg + (size_t)r0 * T_ + s0 + ((tch ^ (r0 & 7)) * 8), Vt + r0 * 64 + tch * 8);
      gld16(Vg + (size_t)r1 * T_ + s0 + ((tch ^ (r1 & 7)) * 8), Vt + r1 * 64 + tch * 8);
    }
    __syncthreads();

    // S^T = K Q^T : K as A-operand, Q as B-operand.
    // C-layout of s[mi]: row = s-local = mi*16+quad*4+r, col = q = l16.
    f32x4 s[4];
#pragma unroll
    for (int mi = 0; mi < 4; mi++) {
      const int row = mi * 16 + l16, sw = row & 7;
      bf16x8 kf0 = *(const bf16x8*)(Ks + row * 64 + ((quad ^ sw) * 8));
      bf16x8 kf1 = *(const bf16x8*)(Ks + row * 64 + (((quad + 4) ^ sw) * 8));
      f32x4 z = {0.f, 0.f, 0.f, 0.f};
      z = __builtin_amdgcn_mfma_f32_16x16x32_bf16(kf0, qf0, z, 0, 0, 0);
      s[mi] = __builtin_amdgcn_mfma_f32_16x16x32_bf16(kf1, qf1, z, 0, 0, 0);
    }

    if (jt == qs) {  // uniform diag branch: mask s > q
#pragma unroll
      for (int mi = 0; mi < 4; mi++)
#pragma unroll
        for (int r = 0; r < 4; r++) {
          float p = EXP2(s[mi][r]);
          p = (s0 + mi * 16 + sloc_base + r > qglob) ? 0.f : p;
          s[mi][r] = p;
          lacc += p;
        }
    } else {
#pragma unroll
      for (int mi = 0; mi < 4; mi++)
#pragma unroll
        for (int r = 0; r < 4; r++) {
          float p = EXP2(s[mi][r]);
          s[mi][r] = p;
          lacc += p;
        }
    }

    // P -> LDS [q=l16][s], packed dwords
#pragma unroll
    for (int mi = 0; mi < 4; mi++) {
      unsigned d0 = pack_bf2(s[mi][0], s[mi][1]);
      unsigned d1 = pack_bf2(s[mi][2], s[mi][3]);
      *(uint2*)(Pw + l16 * 68 + mi * 16 + quad * 4) = make_uint2(d0, d1);
    }

    // O += P V : P as A-operand (m=q=l16, k=s), V^T as B-operand
#pragma unroll
    for (int kk = 0; kk < 2; kk++) {
      bf16x8 pf = *(const bf16x8*)(Pw + l16 * 68 + kk * 32 + quad * 8);
#pragma unroll
      for (int ni = 0; ni < 4; ni++) {
        const int row = ni * 16 + l16, sw = row & 7;
        bf16x8 vf = *(const bf16x8*)(Vt + row * 64 + (((kk * 4 + quad) ^ sw) * 8));
        o[ni] = __builtin_amdgcn_mfma_f32_16x16x32_bf16(pf, vf, o[ni], 0, 0, 0);
      }
    }
  }

  // l: sum across the 4 lanes sharing l16 (quads), then fetch per-row values
  lacc += __shfl_xor(lacc, 16, 64);
  lacc += __shfl_xor(lacc, 32, 64);
  float lr[4];
#pragma unroll
  for (int r = 0; r < 4; r++) lr[r] = __shfl(lacc, quad * 4 + r, 16);  // l for q-row quad*4+r

  if (nch == 1) {
#pragma unroll
    for (int r = 0; r < 4; r++) {
      float inv = 1.0f / lr[r];
      int tq = qs * 64 + wave * 16 + quad * 4 + r;
#pragma unroll
      for (int ni = 0; ni < 4; ni++)
        yb[((size_t)(b * T_ + tq)) * 1024 + h * 64 + ni * 16 + l16] = f2bf(o[ni][r] * inv);
    }
  } else {
    const int slot = 52 * bh + ((qs <= 21) ? ((qs - 11) * 2 + c) : (22 + (qs - 22) * 3 + c));
    unsigned short* pob = po + (size_t)slot * 4096;
#pragma unroll
    for (int r = 0; r < 4; r++) {
      const int row64 = wave * 16 + quad * 4 + r;
#pragma unroll
      for (int ni = 0; ni < 4; ni++)
        pob[row64 * 64 + ni * 16 + l16] = f2bf(o[ni][r]);
      if (l16 == 0) pl[slot * 64 + row64] = lr[r];
    }
  }
}

// ---------------- split-K reduce: rows of strips qs>=11 ----------------
__global__ __launch_bounds__(256) void reduce_kernel(
    const unsigned short* __restrict__ po, const float* __restrict__ pl,
    unsigned short* __restrict__ yb) {
  int idx = blockIdx.x * 256 + threadIdx.x;
  int bh = idx / 21504;          // 1344 rows * 16 colgroups
  int rem = idx - bh * 21504;
  int rr = rem >> 4, cg = rem & 15;
  int qs = 11 + (rr >> 6), row64 = rr & 63;
  int base, nch;
  if (qs <= 21) { base = (qs - 11) * 2; nch = 2; }
  else { base = 22 + (qs - 22) * 3; nch = 3; }
  int b = bh >> 4, h = bh & 15;
  float a0 = 0.f, a1 = 0.f, a2 = 0.f, a3 = 0.f, l = 0.f;
  for (int cc = 0; cc < nch; cc++) {
    int slot = 52 * bh + base + cc;
    const unsigned short* p = po + (size_t)slot * 4096 + row64 * 64 + cg * 4;
    ushort4 uv = *(const ushort4*)p;
    a0 += bf2f(uv.x); a1 += bf2f(uv.y); a2 += bf2f(uv.z); a3 += bf2f(uv.w);
    l += pl[slot * 64 + row64];
  }
  float inv = 1.0f / l;
  int tq = qs * 64 + row64;
  ushort4 w;
  w.x = f2bf(a0 * inv); w.y = f2bf(a1 * inv); w.z = f2bf(a2 * inv); w.w = f2bf(a3 * inv);
  *(ushort4*)(yb + ((size_t)(b * T_ + tq)) * 1024 + h * 64 + cg * 4) = w;
}

// ---------------- launch ----------------
extern "C" void kernel_launch(void* const* d_in, const int* in_sizes, int n_in,
                              void* d_out, int out_size, void* d_ws, size_t ws_size,
                              hipStream_t stream) {
  const float* x = (const float*)d_in[0];       // [B,T,C]
  const float* w_qkv = (const float*)d_in[1];   // [C,3C]
  const float* w_proj = (const float*)d_in[2];  // [C,C]
  float* out = (float*)d_out;                   // [B,T,C] fp32

  // ws layout (shorts). po aliases wqkvT (dead after GEMM1). ~49.7 MB total.
  unsigned short* xb = (unsigned short*)d_ws;                 // 4.19M
  unsigned short* wprojT = xb + (size_t)BT_ * C_;             // 1.05M
  unsigned short* qb = wprojT + (size_t)C_ * C_;              // 4.19M
  unsigned short* kb = qb + (size_t)B_ * H_ * T_ * D_;        // 4.19M
  unsigned short* vb = kb + (size_t)B_ * H_ * T_ * D_;        // 4.19M
  unsigned short* wqkvT = vb + (size_t)B_ * H_ * T_ * D_;     // 3.15M
  unsigned short* po = wqkvT;                                 // 1664 slots * 4096 = 6.82M
  float* pl = (float*)(po + (size_t)1664 * 4096);             // 106K fp32
  unsigned short* yb = xb;  // reuse (x dead after GEMM1)

  prep_kernel<<<dim3(8192), 256, 0, stream>>>(x, xb, w_qkv, wqkvT, w_proj, wprojT);

  gemm_kernel<0><<<dim3(N3_ / 64, BT_ / 128), 256, 0, stream>>>(xb, wqkvT, qb, kb, vb, nullptr);
  attn_kernel<<<dim3(32 * 63), 256, 0, stream>>>(qb, kb, vb, yb, po, pl);
  reduce_kernel<<<dim3(2688), 256, 0, stream>>>(po, pl, yb);
  gemm2_kernel<<<dim3(C_ / 64, BT_ / 64), 256, 0, stream>>>(yb, wprojT, out);
}

// Round 6
// 180.503 us; speedup vs baseline: 1.1950x; 1.0400x over previous
//
#include <hip/hip_runtime.h>
#include <stdint.h>

#define LOG2E 1.4426950408889634f
#define QSCALE 0.18033688011112042f  // 0.125 * log2(e), folded into Q at GEMM1

typedef __attribute__((ext_vector_type(8))) short bf16x8;
typedef __attribute__((ext_vector_type(4))) float f32x4;
typedef __attribute__((ext_vector_type(8))) unsigned short u16x8;

#define B_ 2
#define T_ 2048
#define C_ 1024
#define H_ 16
#define D_ 64
#define BT_ 4096
#define N3_ 3072

#if __has_builtin(__builtin_amdgcn_exp2f)
#define EXP2(x) __builtin_amdgcn_exp2f(x)   // raw v_exp_f32 (inputs bounded, no denorm path)
#else
#define EXP2(x) exp2f(x)
#endif

__device__ __forceinline__ unsigned short f2bf(float f) {
  union { float f; unsigned u; } x; x.f = f;
  return (unsigned short)((x.u + 0x7fffu + ((x.u >> 16) & 1u)) >> 16);
}
__device__ __forceinline__ float bf2f(unsigned short u) {
  union { unsigned u; float f; } x; x.u = ((unsigned)u) << 16;
  return x.f;
}
__device__ __forceinline__ unsigned f2u(float f) {
  union { float f; unsigned u; } x; x.f = f; return x.u;
}
// pack two f32 -> dword of 2 bf16 (low short = a, high = b), round-nearest-away
__device__ __forceinline__ unsigned pack_bf2(float a, float b) {
  return __builtin_amdgcn_perm(f2u(b) + 0x8000u, f2u(a) + 0x8000u, 0x07060302u);
}

// async global->LDS 16B (m97 pattern). LDS dest must be wave-uniform base +
// lane*16 — all call sites below keep lds addr == linear(slot)*16B.
__device__ __forceinline__ void gld16(const unsigned short* g, unsigned short* l) {
  __builtin_amdgcn_global_load_lds(
      (const __attribute__((address_space(1))) unsigned int*)g,
      (__attribute__((address_space(3))) unsigned int*)l, 16, 0, 0);
}

// ---------------- prep (r11-proven): cvt + 2 transposes in one launch ---------
__device__ __forceinline__ void tr32(const float* __restrict__ in,
                                     unsigned short* __restrict__ out,
                                     int K, int N, int b, int nbx, int tid) {
  __shared__ unsigned short tile[32][33];
  const int bx = b % nbx, by = b / nbx;
  const int n0 = bx * 32, k0 = by * 32;
  const int tx = tid & 31, ty = (tid >> 5) * 4;
#pragma unroll
  for (int r = 0; r < 4; r++)
    tile[ty + r][tx] = f2bf(in[(size_t)(k0 + ty + r) * N + n0 + tx]);
  __syncthreads();
#pragma unroll
  for (int r = 0; r < 4; r++)
    out[(size_t)(n0 + ty + r) * K + k0 + tx] = tile[tx][ty + r];
}

__global__ __launch_bounds__(256) void prep_kernel(
    const float* __restrict__ x, unsigned short* __restrict__ xb,
    const float* __restrict__ wq, unsigned short* __restrict__ wqT,
    const float* __restrict__ wp, unsigned short* __restrict__ wpT) {
  const int bid = blockIdx.x, tid = threadIdx.x;
  if (bid < 4096) {
    int i = (bid * 256 + tid) * 4;
    float4 v = *(const float4*)(x + i);
    ushort4 o;
    o.x = f2bf(v.x); o.y = f2bf(v.y); o.z = f2bf(v.z); o.w = f2bf(v.w);
    *(ushort4*)(xb + i) = o;
  } else if (bid < 4096 + 3072) {
    tr32(wq, wqT, 1024, 3072, bid - 4096, 96, tid);
  } else {
    tr32(wp, wpT, 1024, 1024, bid - 7168, 32, tid);
  }
}

// ---------------- GEMM1 (r10 revert — proven 528 TF) -------------------------
// Model (r0-r5 data): aggregate gld16 staging BW saturates at ~12 TB/s in this
// 2-phase structure; TF = 12.2 TB/s * FLOP/staged-byte = 12.2 * 42.7 = 520 ~=
// measured 528. Tile growth (r1-r3) raised FLOP/byte but collapsed staging BW.
// MODE 0: scatter-write q*QSCALE [B,H,T,D], k [B,H,T,D], v [B,H,D,T] bf16
// MODE 1: write fp32 out [m][n] (N=1024)
template <int MODE>
__global__ __launch_bounds__(256) void gemm_kernel(
    const unsigned short* __restrict__ A, const unsigned short* __restrict__ Bt,
    unsigned short* __restrict__ qo, unsigned short* __restrict__ ko,
    unsigned short* __restrict__ vo, float* __restrict__ fo) {
  __shared__ unsigned short As[128 * 64];   // [row][64], chunk-swizzled
  __shared__ unsigned short Bs[64 * 64];    // [row][64], chunk-swizzled
  const int tid = threadIdx.x;
  const int wave = tid >> 6, lane = tid & 63;
  const int quad = lane >> 4, l16 = lane & 15;
  const int wm = (wave >> 1) * 64, wn = (wave & 1) * 32;
  const int m0 = blockIdx.y * 128, n0 = blockIdx.x * 64;

  f32x4 acc[4][2] = {};

  for (int k = 0; k < 1024; k += 64) {
    __syncthreads();
#pragma unroll
    for (int i = 0; i < 4; i++) {
      const int s = tid + 256 * i;
      const int row = s >> 3, ch = s & 7;
      gld16(A + (size_t)(m0 + row) * 1024 + k + ((ch ^ (row & 7)) * 8), As + s * 8);
    }
#pragma unroll
    for (int i = 0; i < 2; i++) {
      const int s = tid + 256 * i;
      const int row = s >> 3, ch = s & 7;
      gld16(Bt + (size_t)(n0 + row) * 1024 + k + ((ch ^ (row & 7)) * 8), Bs + s * 8);
    }
    __syncthreads();
#pragma unroll
    for (int sub = 0; sub < 2; sub++) {
      bf16x8 af[4], bfr[2];
#pragma unroll
      for (int mi = 0; mi < 4; mi++) {
        const int row = wm + mi * 16 + l16;
        af[mi] = *(const bf16x8*)(As + row * 64 + (((sub * 4 + quad) ^ (row & 7)) * 8));
      }
#pragma unroll
      for (int ni = 0; ni < 2; ni++) {
        const int row = wn + ni * 16 + l16;
        bfr[ni] = *(const bf16x8*)(Bs + row * 64 + (((sub * 4 + quad) ^ (row & 7)) * 8));
      }
#pragma unroll
      for (int mi = 0; mi < 4; mi++)
#pragma unroll
        for (int ni = 0; ni < 2; ni++)
          acc[mi][ni] = __builtin_amdgcn_mfma_f32_16x16x32_bf16(af[mi], bfr[ni], acc[mi][ni], 0, 0, 0);
    }
  }

  // epilogue: C/D layout col=l16, row=quad*4+r (m89/m91-verified)
  if (MODE == 0) {
    const int part = n0 >> 10;          // block-uniform
    const int hh = (n0 >> 6) & 15;      // block-uniform
#pragma unroll
    for (int mi = 0; mi < 4; mi++) {
#pragma unroll
      for (int r = 0; r < 4; r++) {
        const int m = m0 + wm + mi * 16 + quad * 4 + r;
        const int b = m >> 11, t = m & 2047;
#pragma unroll
        for (int ni = 0; ni < 2; ni++) {
          const int d = wn + ni * 16 + l16;
          float val = acc[mi][ni][r];
          if (part == 0) val *= QSCALE;   // fold softmax scale into Q (fp32, free)
          const unsigned short bv = f2bf(val);
          if (part == 0)
            qo[((size_t)(b * H_ + hh) * T_ + t) * D_ + d] = bv;
          else if (part == 1)
            ko[((size_t)(b * H_ + hh) * T_ + t) * D_ + d] = bv;
          else
            vo[((size_t)(b * H_ + hh) * D_ + d) * T_ + t] = bv;  // V pre-transposed [B,H,D,T]
        }
      }
    }
  } else {
#pragma unroll
    for (int mi = 0; mi < 4; mi++)
#pragma unroll
      for (int r = 0; r < 4; r++) {
        const int m = m0 + wm + mi * 16 + quad * 4 + r;
#pragma unroll
        for (int ni = 0; ni < 2; ni++)
          fo[(size_t)m * 1024 + n0 + wn + ni * 16 + l16] = acc[mi][ni][r];
      }
  }
}

// ---------------- GEMM2: 64x64 tile, high-occupancy 2-phase (r5, kept) -------
__global__ __launch_bounds__(256) void gemm2_kernel(
    const unsigned short* __restrict__ A, const unsigned short* __restrict__ Bt,
    float* __restrict__ fo) {
  __shared__ unsigned short As[64 * 64];   // 8KB, chunk-swizzled
  __shared__ unsigned short Bs[64 * 64];   // 8KB, chunk-swizzled
  const int tid = threadIdx.x;
  const int wave = tid >> 6, lane = tid & 63;
  const int quad = lane >> 4, l16 = lane & 15;
  const int wm = (wave >> 1) * 32, wn = (wave & 1) * 32;
  const int m0 = blockIdx.y * 64, n0 = blockIdx.x * 64;

  f32x4 acc[2][2] = {};

  for (int k = 0; k < 1024; k += 64) {
    __syncthreads();
#pragma unroll
    for (int i = 0; i < 2; i++) {
      const int s = tid + 256 * i;
      const int row = s >> 3, ch = s & 7;
      gld16(A + (size_t)(m0 + row) * 1024 + k + ((ch ^ (row & 7)) * 8), As + s * 8);
      gld16(Bt + (size_t)(n0 + row) * 1024 + k + ((ch ^ (row & 7)) * 8), Bs + s * 8);
    }
    __syncthreads();
#pragma unroll
    for (int sub = 0; sub < 2; sub++) {
      bf16x8 af[2], bfr[2];
#pragma unroll
      for (int mi = 0; mi < 2; mi++) {
        const int row = wm + mi * 16 + l16;
        af[mi] = *(const bf16x8*)(As + row * 64 + (((sub * 4 + quad) ^ (row & 7)) * 8));
      }
#pragma unroll
      for (int ni = 0; ni < 2; ni++) {
        const int row = wn + ni * 16 + l16;
        bfr[ni] = *(const bf16x8*)(Bs + row * 64 + (((sub * 4 + quad) ^ (row & 7)) * 8));
      }
#pragma unroll
      for (int mi = 0; mi < 2; mi++)
#pragma unroll
        for (int ni = 0; ni < 2; ni++)
          acc[mi][ni] = __builtin_amdgcn_mfma_f32_16x16x32_bf16(af[mi], bfr[ni], acc[mi][ni], 0, 0, 0);
    }
  }

  // epilogue: C/D layout col=l16, row=quad*4+r
#pragma unroll
  for (int mi = 0; mi < 2; mi++)
#pragma unroll
    for (int r = 0; r < 4; r++) {
      const int m = m0 + wm + mi * 16 + quad * 4 + r;
#pragma unroll
      for (int ni = 0; ni < 2; ni++)
        fo[(size_t)m * 1024 + n0 + wn + ni * 16 + l16] = acc[mi][ni][r];
    }
}

// ---------------- flash attention: Q-tile 128, 8 waves (r6) -------------------
// r5 analysis: attn stages only 5.8 TB/s (not staging-BW-bound) — it is
// ROUND-count-bound (16.9k serialized stage->compute rounds). Doubling the
// Q-tile to 128 rows (8 waves, 512 thr) processes 2x q-rows per staged 16KB
// K/V tile: rounds 16.9k -> 8.7k, per-wave per-tile work unchanged (16 MFMA).
// LDS 33.8KB -> 4 blocks/CU (16 waves). Chunk table (longest-first): nch=1
// for qs<=7 (up to 16 tiles), nch=2 for qs 8-9, nch=3 for qs 10-15.
// Masking generalizes to jt >= 2*qs (both diagonal tiles; fully-masked waves
// produce exact zeros). po: 704 slots x 128x64 bf16 (ws stays under 47.6MB).
__device__ const unsigned char CHUNK_TAB[30] = {
    // (qs<<4)|(c<<2)|nch, sorted by chunk length desc
    0x71, 0x61, 0x51, 0xF7, 0xFB, 0x41, 0x92, 0x96, 0xDB, 0xE3,
    0xE7, 0xEB, 0xF3, 0x82, 0x86, 0xC7, 0xCB, 0xD3, 0xD7, 0x31,
    0xAB, 0xB3, 0xB7, 0xBB, 0xC3, 0xA3, 0xA7, 0x21, 0x11, 0x01};

__global__ __launch_bounds__(512) void attn_kernel(
    const unsigned short* __restrict__ qb, const unsigned short* __restrict__ kb,
    const unsigned short* __restrict__ vb, unsigned short* __restrict__ yb,
    unsigned short* __restrict__ po, float* __restrict__ pl) {
  const int tid = threadIdx.x;
  const int wave = tid >> 6, lane = tid & 63;
  const int quad = lane >> 4, l16 = lane & 15;

  const int bid = blockIdx.x;
  const int bh = bid & 31;          // XCD-local: all chunks of bh on one XCD
  const int u = bid >> 5;           // 0..29, longest chunks first
  const int e = CHUNK_TAB[u];
  const int qs = e >> 4, c = (e >> 2) & 3, nch = e & 3;
  const int nt = 2 * qs + 2;
  const int j0 = c * nt / nch, j1 = (c + 1) * nt / nch;
  const int b = bh >> 4, h = bh & 15;

  __shared__ unsigned short Ks[64 * 64];     // [s][d], chunk-swizzled, 8KB
  __shared__ unsigned short Vt[64 * 64];     // [d][s], chunk-swizzled, 8KB
  __shared__ unsigned short Ps[8 * 16 * 68]; // per-wave P [q][s], stride 68
  unsigned short* Pw = Ps + wave * 16 * 68;

  const unsigned short* Qg = qb + (size_t)bh * T_ * D_;
  const unsigned short* Kg = kb + (size_t)bh * T_ * D_;
  const unsigned short* Vg = vb + (size_t)bh * D_ * T_;

  // Q fragment (B-operand: n=q=l16, k=d=quad*8+j); wave owns 16 q-rows
  const int qrow0 = qs * 128 + wave * 16;
  const unsigned short* qp = Qg + (size_t)(qrow0 + l16) * D_ + quad * 8;
  bf16x8 qf0 = *(const bf16x8*)qp, qf1 = *(const bf16x8*)(qp + 32);

  f32x4 o[4] = {};
  float lacc = 0.f;
  const int qglob = qrow0 + l16;                 // this lane's q (S^T: col=l16)
  const int sloc_base = quad * 4;                // s-local row base (S^T: row=quad*4+r)
  const int diag0 = 2 * qs;                      // first tile needing masking

  const int trow = tid >> 3, tch = tid & 7;      // 512 thr: rows 0..63, ch 0..7

  for (int jt = j0; jt < j1; jt++) {
    const int s0 = jt * 64;
    __syncthreads();
    {
      gld16(Kg + (size_t)(s0 + trow) * D_ + ((tch ^ (trow & 7)) * 8), Ks + trow * 64 + tch * 8);
      gld16(Vg + (size_t)trow * T_ + s0 + ((tch ^ (trow & 7)) * 8), Vt + trow * 64 + tch * 8);
    }
    __syncthreads();

    // S^T = K Q^T : K as A-operand, Q as B-operand.
    // C-layout of s[mi]: row = s-local = mi*16+quad*4+r, col = q = l16.
    f32x4 s[4];
#pragma unroll
    for (int mi = 0; mi < 4; mi++) {
      const int row = mi * 16 + l16, sw = row & 7;
      bf16x8 kf0 = *(const bf16x8*)(Ks + row * 64 + ((quad ^ sw) * 8));
      bf16x8 kf1 = *(const bf16x8*)(Ks + row * 64 + (((quad + 4) ^ sw) * 8));
      f32x4 z = {0.f, 0.f, 0.f, 0.f};
      z = __builtin_amdgcn_mfma_f32_16x16x32_bf16(kf0, qf0, z, 0, 0, 0);
      s[mi] = __builtin_amdgcn_mfma_f32_16x16x32_bf16(kf1, qf1, z, 0, 0, 0);
    }

    if (jt >= diag0) {  // uniform diag branch: mask s > q (both diagonal tiles)
#pragma unroll
      for (int mi = 0; mi < 4; mi++)
#pragma unroll
        for (int r = 0; r < 4; r++) {
          float p = EXP2(s[mi][r]);
          p = (s0 + mi * 16 + sloc_base + r > qglob) ? 0.f : p;
          s[mi][r] = p;
          lacc += p;
        }
    } else {
#pragma unroll
      for (int mi = 0; mi < 4; mi++)
#pragma unroll
        for (int r = 0; r < 4; r++) {
          float p = EXP2(s[mi][r]);
          s[mi][r] = p;
          lacc += p;
        }
    }

    // P -> LDS [q=l16][s], packed dwords
#pragma unroll
    for (int mi = 0; mi < 4; mi++) {
      unsigned d0 = pack_bf2(s[mi][0], s[mi][1]);
      unsigned d1 = pack_bf2(s[mi][2], s[mi][3]);
      *(uint2*)(Pw + l16 * 68 + mi * 16 + quad * 4) = make_uint2(d0, d1);
    }

    // O += P V : P as A-operand (m=q=l16, k=s), V^T as B-operand
#pragma unroll
    for (int kk = 0; kk < 2; kk++) {
      bf16x8 pf = *(const bf16x8*)(Pw + l16 * 68 + kk * 32 + quad * 8);
#pragma unroll
      for (int ni = 0; ni < 4; ni++) {
        const int row = ni * 16 + l16, sw = row & 7;
        bf16x8 vf = *(const bf16x8*)(Vt + row * 64 + (((kk * 4 + quad) ^ sw) * 8));
        o[ni] = __builtin_amdgcn_mfma_f32_16x16x32_bf16(pf, vf, o[ni], 0, 0, 0);
      }
    }
  }

  // l: sum across the 4 lanes sharing l16 (quads), then fetch per-row values
  lacc += __shfl_xor(lacc, 16, 64);
  lacc += __shfl_xor(lacc, 32, 64);
  float lr[4];
#pragma unroll
  for (int r = 0; r < 4; r++) lr[r] = __shfl(lacc, quad * 4 + r, 16);  // l for q-row quad*4+r

  if (nch == 1) {
#pragma unroll
    for (int r = 0; r < 4; r++) {
      float inv = 1.0f / lr[r];
      int tq = qrow0 + quad * 4 + r;
#pragma unroll
      for (int ni = 0; ni < 4; ni++)
        yb[((size_t)(b * T_ + tq)) * 1024 + h * 64 + ni * 16 + l16] = f2bf(o[ni][r] * inv);
    }
  } else {
    // split slots: qs 8,9 -> (qs-8)*2 + c; qs 10..15 -> 4 + (qs-10)*3 + c
    const int slot = 22 * bh + ((qs < 10) ? ((qs - 8) * 2 + c) : (4 + (qs - 10) * 3 + c));
    unsigned short* pob = po + (size_t)slot * 8192;
#pragma unroll
    for (int r = 0; r < 4; r++) {
      const int row128 = wave * 16 + quad * 4 + r;
#pragma unroll
      for (int ni = 0; ni < 4; ni++)
        pob[row128 * 64 + ni * 16 + l16] = f2bf(o[ni][r]);
      if (l16 == 0) pl[slot * 128 + row128] = lr[r];
    }
  }
}

// ---------------- split-K reduce: q-blocks qs>=8 (128 rows each) --------------
__global__ __launch_bounds__(256) void reduce_kernel(
    const unsigned short* __restrict__ po, const float* __restrict__ pl,
    unsigned short* __restrict__ yb) {
  int idx = blockIdx.x * 256 + threadIdx.x;   // 32 bh * 8 qsplit * 128 rows * 16 cg
  int bh = idx >> 14;
  int rem = idx & 16383;
  int qs = 8 + (rem >> 11);
  int row128 = (rem >> 4) & 127;
  int cg = rem & 15;
  int base, nch;
  if (qs < 10) { base = (qs - 8) * 2; nch = 2; }
  else { base = 4 + (qs - 10) * 3; nch = 3; }
  int b = bh >> 4, h = bh & 15;
  float a0 = 0.f, a1 = 0.f, a2 = 0.f, a3 = 0.f, l = 0.f;
  for (int cc = 0; cc < nch; cc++) {
    int slot = 22 * bh + base + cc;
    const unsigned short* p = po + (size_t)slot * 8192 + row128 * 64 + cg * 4;
    ushort4 uv = *(const ushort4*)p;
    a0 += bf2f(uv.x); a1 += bf2f(uv.y); a2 += bf2f(uv.z); a3 += bf2f(uv.w);
    l += pl[slot * 128 + row128];
  }
  float inv = 1.0f / l;
  int tq = qs * 128 + row128;
  ushort4 w;
  w.x = f2bf(a0 * inv); w.y = f2bf(a1 * inv); w.z = f2bf(a2 * inv); w.w = f2bf(a3 * inv);
  *(ushort4*)(yb + ((size_t)(b * T_ + tq)) * 1024 + h * 64 + cg * 4) = w;
}

// ---------------- launch ----------------
extern "C" void kernel_launch(void* const* d_in, const int* in_sizes, int n_in,
                              void* d_out, int out_size, void* d_ws, size_t ws_size,
                              hipStream_t stream) {
  const float* x = (const float*)d_in[0];       // [B,T,C]
  const float* w_qkv = (const float*)d_in[1];   // [C,3C]
  const float* w_proj = (const float*)d_in[2];  // [C,C]
  float* out = (float*)d_out;                   // [B,T,C] fp32

  // ws layout (shorts). po aliases wqkvT (dead after GEMM1). ~47.6 MB total.
  unsigned short* xb = (unsigned short*)d_ws;                 // 4.19M shorts
  unsigned short* wprojT = xb + (size_t)BT_ * C_;             // 1.05M
  unsigned short* qb = wprojT + (size_t)C_ * C_;              // 4.19M
  unsigned short* kb = qb + (size_t)B_ * H_ * T_ * D_;        // 4.19M
  unsigned short* vb = kb + (size_t)B_ * H_ * T_ * D_;        // 4.19M
  unsigned short* wqkvT = vb + (size_t)B_ * H_ * T_ * D_;     // 3.15M
  unsigned short* po = wqkvT;                                 // 704 slots * 8192 = 5.77M
  float* pl = (float*)(po + (size_t)704 * 8192);              // 90K fp32
  unsigned short* yb = xb;  // reuse (x dead after GEMM1)

  prep_kernel<<<dim3(8192), 256, 0, stream>>>(x, xb, w_qkv, wqkvT, w_proj, wprojT);

  gemm_kernel<0><<<dim3(N3_ / 64, BT_ / 128), 256, 0, stream>>>(xb, wqkvT, qb, kb, vb, nullptr);
  attn_kernel<<<dim3(32 * 30), 512, 0, stream>>>(qb, kb, vb, yb, po, pl);
  reduce_kernel<<<dim3(2048), 256, 0, stream>>>(po, pl, yb);
  gemm2_kernel<<<dim3(C_ / 64, BT_ / 64), 256, 0, stream>>>(yb, wprojT, out);
}